// Round 1
// baseline (1227.448 us; speedup 1.0000x reference)
//
#include <hip/hip_runtime.h>
#include <hip/hip_bf16.h>

#define N_NODES 50000
#define E_EDGES 800000
#define ET (E_EDGES + N_NODES)
#define G_GRAPHS 64
#define IN_F 128
#define HID 64
#define HEADS 4
#define HC (HID * HEADS)
#define NC 2
#define SLOPE 0.2f

// ---------------- CSR build ----------------

__global__ void count_kernel(const int* __restrict__ ei, int* __restrict__ cnt) {
  int e = blockIdx.x * blockDim.x + threadIdx.x;
  if (e >= ET) return;
  int dst = (e < E_EDGES) ? ei[E_EDGES + e] : (e - E_EDGES);
  atomicAdd(&cnt[dst], 1);
}

__global__ __launch_bounds__(1024) void scan_kernel(const int* __restrict__ cnt,
                                                    int* __restrict__ rowptr,
                                                    int* __restrict__ cursor) {
  __shared__ int sdata[1024];
  __shared__ int sh_run;
  int tid = threadIdx.x;
  if (tid == 0) sh_run = 0;
  __syncthreads();
  for (int base = 0; base < N_NODES; base += 1024) {
    int i = base + tid;
    int v = (i < N_NODES) ? cnt[i] : 0;
    sdata[tid] = v;
    __syncthreads();
    for (int off = 1; off < 1024; off <<= 1) {
      int t = (tid >= off) ? sdata[tid - off] : 0;
      __syncthreads();
      sdata[tid] += t;
      __syncthreads();
    }
    int run = sh_run;
    if (i < N_NODES) {
      rowptr[i + 1] = run + sdata[tid];
      cursor[i] = run + sdata[tid] - v;
      if (i == 0) rowptr[0] = 0;
    }
    __syncthreads();
    if (tid == 0) sh_run += sdata[1023];
    __syncthreads();
  }
}

__global__ void scatter_kernel(const int* __restrict__ ei, int* __restrict__ cursor,
                               int* __restrict__ csr_src) {
  int e = blockIdx.x * blockDim.x + threadIdx.x;
  if (e >= ET) return;
  int src, dst;
  if (e < E_EDGES) { src = ei[e]; dst = ei[E_EDGES + e]; }
  else { src = e - E_EDGES; dst = src; }
  int pos = atomicAdd(&cursor[dst], 1);
  csr_src[pos] = src;
}

// ---------------- GEMM h = A @ W^T, fused attention-coeff epilogue ----------------
// A: [N_NODES, K] row-major, W: [HC, K] row-major. Block computes 64 rows x 64 cols.
// 64-col tile == exactly one head, so als/ald reduced in-epilogue.

template <int K>
__global__ __launch_bounds__(256) void gemm_al_kernel(
    const float* __restrict__ A, const float* __restrict__ W,
    const float* __restrict__ a_s, const float* __restrict__ a_d,
    float* __restrict__ hbuf, float* __restrict__ als, float* __restrict__ ald) {
  __shared__ float As[64][33];
  __shared__ float Bs[64][33];
  int tid = threadIdx.x;
  int mt = blockIdx.x;
  int head = blockIdx.y;
  int jt = head * 64;
  int tr = tid >> 4;   // 0..15
  int tc = tid & 15;   // 0..15
  float acc[4][4] = {};
  int lr = tid >> 2;         // 0..63 (row of A tile / row of W tile)
  int kq = (tid & 3) * 8;    // 0,8,16,24

  for (int k0 = 0; k0 < K; k0 += 32) {
    int grow = mt * 64 + lr;
    float4 a0, a1;
    if (grow < N_NODES) {
      a0 = *(const float4*)&A[(size_t)grow * K + k0 + kq];
      a1 = *(const float4*)&A[(size_t)grow * K + k0 + kq + 4];
    } else {
      a0 = make_float4(0.f, 0.f, 0.f, 0.f);
      a1 = a0;
    }
    float4 b0 = *(const float4*)&W[(size_t)(jt + lr) * K + k0 + kq];
    float4 b1 = *(const float4*)&W[(size_t)(jt + lr) * K + k0 + kq + 4];
    As[lr][kq + 0] = a0.x; As[lr][kq + 1] = a0.y; As[lr][kq + 2] = a0.z; As[lr][kq + 3] = a0.w;
    As[lr][kq + 4] = a1.x; As[lr][kq + 5] = a1.y; As[lr][kq + 6] = a1.z; As[lr][kq + 7] = a1.w;
    Bs[lr][kq + 0] = b0.x; Bs[lr][kq + 1] = b0.y; Bs[lr][kq + 2] = b0.z; Bs[lr][kq + 3] = b0.w;
    Bs[lr][kq + 4] = b1.x; Bs[lr][kq + 5] = b1.y; Bs[lr][kq + 6] = b1.z; Bs[lr][kq + 7] = b1.w;
    __syncthreads();
#pragma unroll
    for (int k = 0; k < 32; k++) {
      float av[4], bv[4];
#pragma unroll
      for (int i = 0; i < 4; i++) av[i] = As[tr * 4 + i][k];
#pragma unroll
      for (int j = 0; j < 4; j++) bv[j] = Bs[tc * 4 + j][k];
#pragma unroll
      for (int i = 0; i < 4; i++)
#pragma unroll
        for (int j = 0; j < 4; j++) acc[i][j] += av[i] * bv[j];
    }
    __syncthreads();
  }

  // store h tile
#pragma unroll
  for (int i = 0; i < 4; i++) {
    int row = mt * 64 + tr * 4 + i;
    if (row < N_NODES) {
      float4 o = make_float4(acc[i][0], acc[i][1], acc[i][2], acc[i][3]);
      *(float4*)&hbuf[(size_t)row * HC + jt + tc * 4] = o;
    }
  }

  // attention coefficient epilogue: als[row,head] = sum_c h*a_src, ald likewise
  float4 asw = *(const float4*)&a_s[head * HID + tc * 4];
  float4 adw = *(const float4*)&a_d[head * HID + tc * 4];
#pragma unroll
  for (int i = 0; i < 4; i++) {
    float ps = acc[i][0] * asw.x + acc[i][1] * asw.y + acc[i][2] * asw.z + acc[i][3] * asw.w;
    float pd = acc[i][0] * adw.x + acc[i][1] * adw.y + acc[i][2] * adw.z + acc[i][3] * adw.w;
#pragma unroll
    for (int m = 1; m < 16; m <<= 1) {
      ps += __shfl_xor(ps, m, 64);
      pd += __shfl_xor(pd, m, 64);
    }
    if (tc == 0) {
      int row = mt * 64 + tr * 4 + i;
      if (row < N_NODES) {
        als[row * HEADS + head] = ps;
        ald[row * HEADS + head] = pd;
      }
    }
  }
}

// ---------------- per-destination softmax + aggregate (one wave per node) ----------------

template <bool RELU>
__global__ __launch_bounds__(256) void agg_kernel(
    const float* __restrict__ hbuf, const float* __restrict__ als,
    const float* __restrict__ ald, const int* __restrict__ rowptr,
    const int* __restrict__ csr_src, const float* __restrict__ bias,
    float* __restrict__ out) {
  int wave = threadIdx.x >> 6;
  int lane = threadIdx.x & 63;
  int v = blockIdx.x * 4 + wave;
  if (v >= N_NODES) return;
  int head = lane >> 4;
  float myald = ald[v * HEADS + head];
  int beg = rowptr[v], end = rowptr[v + 1];

  float m = -1e30f;
  for (int i = beg; i < end; i++) {
    int s = csr_src[i];
    float sc = als[s * HEADS + head] + myald;
    sc = sc > 0.f ? sc : SLOPE * sc;
    m = fmaxf(m, sc);
  }
  float den = 0.f;
  float4 acc = make_float4(0.f, 0.f, 0.f, 0.f);
  for (int i = beg; i < end; i++) {
    int s = csr_src[i];
    float sc = als[s * HEADS + head] + myald;
    sc = sc > 0.f ? sc : SLOPE * sc;
    float ex = expf(sc - m);
    den += ex;
    float4 hv = *(const float4*)&hbuf[(size_t)s * HC + lane * 4];
    acc.x += hv.x * ex; acc.y += hv.y * ex; acc.z += hv.z * ex; acc.w += hv.w * ex;
  }
  float inv = 1.0f / (den + 1e-16f);
  float4 bv = *(const float4*)&bias[lane * 4];
  float4 o;
  o.x = acc.x * inv + bv.x;
  o.y = acc.y * inv + bv.y;
  o.z = acc.z * inv + bv.z;
  o.w = acc.w * inv + bv.w;
  if (RELU) {
    o.x = fmaxf(o.x, 0.f); o.y = fmaxf(o.y, 0.f);
    o.z = fmaxf(o.z, 0.f); o.w = fmaxf(o.w, 0.f);
  }
  *(float4*)&out[(size_t)v * HC + lane * 4] = o;
}

// ---------------- global mean pool (batch is sorted) ----------------

__global__ __launch_bounds__(256) void pool_kernel(const float* __restrict__ abuf,
                                                   const int* __restrict__ batch,
                                                   float* __restrict__ pooled) {
  int g = blockIdx.x;
  int c = threadIdx.x;  // 256 cols
  // lower_bound(batch, g) and lower_bound(batch, g+1)
  int lo = 0, hi = N_NODES;
  while (lo < hi) { int mid = (lo + hi) >> 1; if (batch[mid] < g) lo = mid + 1; else hi = mid; }
  int start = lo;
  hi = N_NODES;
  while (lo < hi) { int mid = (lo + hi) >> 1; if (batch[mid] < g + 1) lo = mid + 1; else hi = mid; }
  int end = lo;
  float acc = 0.f;
  for (int n = start; n < end; n++) acc += abuf[(size_t)n * HC + c];
  pooled[g * HC + c] = acc / fmaxf((float)(end - start), 1.0f);
}

// ---------------- MLP head ----------------

__global__ __launch_bounds__(64) void mlp_kernel(const float* __restrict__ pooled,
                                                 const float* __restrict__ w1,
                                                 const float* __restrict__ b1,
                                                 const float* __restrict__ w2,
                                                 const float* __restrict__ b2,
                                                 float* __restrict__ out) {
  int g = blockIdx.x;
  int j = threadIdx.x;  // 64
  __shared__ float z[HID];
  float acc = b1[j];
  for (int k = 0; k < HC; k++) acc += pooled[g * HC + k] * w1[j * HC + k];
  z[j] = fmaxf(acc, 0.f);
  __syncthreads();
  if (j < NC) {
    float o = b2[j];
    for (int k = 0; k < HID; k++) o += z[k] * w2[j * HID + k];
    out[g * NC + j] = o;
  }
}

// ---------------- launch ----------------

extern "C" void kernel_launch(void* const* d_in, const int* in_sizes, int n_in,
                              void* d_out, int out_size, void* d_ws, size_t ws_size,
                              hipStream_t stream) {
  const float* x    = (const float*)d_in[0];
  const int*   ei   = (const int*)d_in[1];
  const int*   batch= (const int*)d_in[2];
  const float* W1   = (const float*)d_in[3];
  const float* as1  = (const float*)d_in[4];
  const float* ad1  = (const float*)d_in[5];
  const float* b1   = (const float*)d_in[6];
  const float* W2   = (const float*)d_in[7];
  const float* as2  = (const float*)d_in[8];
  const float* ad2  = (const float*)d_in[9];
  const float* b2   = (const float*)d_in[10];
  const float* W3   = (const float*)d_in[11];
  const float* as3  = (const float*)d_in[12];
  const float* ad3  = (const float*)d_in[13];
  const float* b3   = (const float*)d_in[14];
  const float* fc1w = (const float*)d_in[15];
  const float* fc1b = (const float*)d_in[16];
  const float* fc2w = (const float*)d_in[17];
  const float* fc2b = (const float*)d_in[18];
  float* out = (float*)d_out;

  char* ws = (char*)d_ws;
  size_t off = 0;
  float* hbuf   = (float*)(ws + off); off += (size_t)N_NODES * HC * 4;      // 51.2 MB
  float* abuf   = (float*)(ws + off); off += (size_t)N_NODES * HC * 4;      // 51.2 MB
  float* als    = (float*)(ws + off); off += (size_t)N_NODES * HEADS * 4;   // 0.8 MB
  float* ald    = (float*)(ws + off); off += (size_t)N_NODES * HEADS * 4;   // 0.8 MB
  float* pooled = (float*)(ws + off); off += (size_t)G_GRAPHS * HC * 4;     // 64 KB
  int*   cnt    = (int*)(ws + off);   off += (size_t)N_NODES * 4;           // 0.2 MB
  int*   cursor = (int*)(ws + off);   off += (size_t)N_NODES * 4;           // 0.2 MB
  int*   csrsrc = (int*)(ws + off);   off += (size_t)ET * 4;                // 3.4 MB
  int*   rowptr = (int*)(ws + off);   off += (size_t)(N_NODES + 1) * 4;

  // --- CSR build (topology shared by all 3 layers) ---
  hipMemsetAsync(cnt, 0, (size_t)N_NODES * 4, stream);
  count_kernel<<<(ET + 255) / 256, 256, 0, stream>>>(ei, cnt);
  scan_kernel<<<1, 1024, 0, stream>>>(cnt, rowptr, cursor);
  scatter_kernel<<<(ET + 255) / 256, 256, 0, stream>>>(ei, cursor, csrsrc);

  dim3 gemm_grid((N_NODES + 63) / 64, HEADS);
  int agg_grid = (N_NODES + 3) / 4;

  // --- layer 1 ---
  gemm_al_kernel<IN_F><<<gemm_grid, 256, 0, stream>>>(x, W1, as1, ad1, hbuf, als, ald);
  agg_kernel<true><<<agg_grid, 256, 0, stream>>>(hbuf, als, ald, rowptr, csrsrc, b1, abuf);
  // --- layer 2 ---
  gemm_al_kernel<HC><<<gemm_grid, 256, 0, stream>>>(abuf, W2, as2, ad2, hbuf, als, ald);
  agg_kernel<true><<<agg_grid, 256, 0, stream>>>(hbuf, als, ald, rowptr, csrsrc, b2, abuf);
  // --- layer 3 ---
  gemm_al_kernel<HC><<<gemm_grid, 256, 0, stream>>>(abuf, W3, as3, ad3, hbuf, als, ald);
  agg_kernel<false><<<agg_grid, 256, 0, stream>>>(hbuf, als, ald, rowptr, csrsrc, b3, abuf);

  // --- pool + MLP ---
  pool_kernel<<<G_GRAPHS, 256, 0, stream>>>(abuf, batch, pooled);
  mlp_kernel<<<G_GRAPHS, 64, 0, stream>>>(pooled, fc1w, fc1b, fc2w, fc2b, out);
}

// Round 2
// 1024.303 us; speedup vs baseline: 1.1983x; 1.1983x over previous
//
#include <hip/hip_runtime.h>
#include <hip/hip_bf16.h>

#define N_NODES 50000
#define E_EDGES 800000
#define ET (E_EDGES + N_NODES)
#define G_GRAPHS 64
#define IN_F 128
#define HID 64
#define HEADS 4
#define HC (HID * HEADS)
#define NC 2
#define SLOPE 0.2f
#define POOL_CHUNK 128

// ---------------- CSR build ----------------

__global__ void count_kernel(const int* __restrict__ ei, int* __restrict__ cnt) {
  int e = blockIdx.x * blockDim.x + threadIdx.x;
  if (e >= ET) return;
  int dst = (e < E_EDGES) ? ei[E_EDGES + e] : (e - E_EDGES);
  atomicAdd(&cnt[dst], 1);
}

// wave-shuffle hierarchical scan: 3 syncs per 1024-chunk instead of ~20
__global__ __launch_bounds__(1024) void scan_kernel(const int* __restrict__ cnt,
                                                    int* __restrict__ rowptr,
                                                    int* __restrict__ cursor) {
  __shared__ int wsum[16];
  __shared__ int sh_run;
  int tid = threadIdx.x;
  int wave = tid >> 6;
  int lane = tid & 63;
  if (tid == 0) sh_run = 0;
  __syncthreads();
  for (int base = 0; base < N_NODES; base += 1024) {
    int i = base + tid;
    int v = (i < N_NODES) ? cnt[i] : 0;
    int x = v;
#pragma unroll
    for (int off = 1; off < 64; off <<= 1) {
      int t = __shfl_up(x, off, 64);
      if (lane >= off) x += t;
    }
    if (lane == 63) wsum[wave] = x;
    __syncthreads();
    if (wave == 0 && lane < 16) {
      int y = wsum[lane];
#pragma unroll
      for (int off = 1; off < 16; off <<= 1) {
        int t = __shfl_up(y, off, 16);
        if ((lane & 15) >= off) y += t;
      }
      wsum[lane] = y;
    }
    __syncthreads();
    int run = sh_run;
    int incl = run + x + (wave > 0 ? wsum[wave - 1] : 0);
    if (i < N_NODES) {
      rowptr[i + 1] = incl;
      cursor[i] = incl - v;
      if (i == 0) rowptr[0] = 0;
    }
    __syncthreads();
    if (tid == 0) sh_run = run + wsum[15];
    __syncthreads();
  }
}

__global__ void scatter_kernel(const int* __restrict__ ei, int* __restrict__ cursor,
                               int* __restrict__ csr_src) {
  int e = blockIdx.x * blockDim.x + threadIdx.x;
  if (e >= ET) return;
  int src, dst;
  if (e < E_EDGES) { src = ei[e]; dst = ei[E_EDGES + e]; }
  else { src = e - E_EDGES; dst = src; }
  int pos = atomicAdd(&cursor[dst], 1);
  csr_src[pos] = src;
}

// ---------------- GEMM h = A @ W^T, fused attention-coeff epilogue ----------------

template <int K>
__global__ __launch_bounds__(256) void gemm_al_kernel(
    const float* __restrict__ A, const float* __restrict__ W,
    const float* __restrict__ a_s, const float* __restrict__ a_d,
    float* __restrict__ hbuf, float* __restrict__ als, float* __restrict__ ald) {
  __shared__ float As[64][33];
  __shared__ float Bs[64][33];
  int tid = threadIdx.x;
  int mt = blockIdx.x;
  int head = blockIdx.y;
  int jt = head * 64;
  int tr = tid >> 4;   // 0..15
  int tc = tid & 15;   // 0..15
  float acc[4][4] = {};
  int lr = tid >> 2;         // 0..63
  int kq = (tid & 3) * 8;    // 0,8,16,24

  for (int k0 = 0; k0 < K; k0 += 32) {
    int grow = mt * 64 + lr;
    float4 a0, a1;
    if (grow < N_NODES) {
      a0 = *(const float4*)&A[(size_t)grow * K + k0 + kq];
      a1 = *(const float4*)&A[(size_t)grow * K + k0 + kq + 4];
    } else {
      a0 = make_float4(0.f, 0.f, 0.f, 0.f);
      a1 = a0;
    }
    float4 b0 = *(const float4*)&W[(size_t)(jt + lr) * K + k0 + kq];
    float4 b1 = *(const float4*)&W[(size_t)(jt + lr) * K + k0 + kq + 4];
    As[lr][kq + 0] = a0.x; As[lr][kq + 1] = a0.y; As[lr][kq + 2] = a0.z; As[lr][kq + 3] = a0.w;
    As[lr][kq + 4] = a1.x; As[lr][kq + 5] = a1.y; As[lr][kq + 6] = a1.z; As[lr][kq + 7] = a1.w;
    Bs[lr][kq + 0] = b0.x; Bs[lr][kq + 1] = b0.y; Bs[lr][kq + 2] = b0.z; Bs[lr][kq + 3] = b0.w;
    Bs[lr][kq + 4] = b1.x; Bs[lr][kq + 5] = b1.y; Bs[lr][kq + 6] = b1.z; Bs[lr][kq + 7] = b1.w;
    __syncthreads();
#pragma unroll
    for (int k = 0; k < 32; k++) {
      float av[4], bv[4];
#pragma unroll
      for (int i = 0; i < 4; i++) av[i] = As[tr * 4 + i][k];
#pragma unroll
      for (int j = 0; j < 4; j++) bv[j] = Bs[tc * 4 + j][k];
#pragma unroll
      for (int i = 0; i < 4; i++)
#pragma unroll
        for (int j = 0; j < 4; j++) acc[i][j] += av[i] * bv[j];
    }
    __syncthreads();
  }

#pragma unroll
  for (int i = 0; i < 4; i++) {
    int row = mt * 64 + tr * 4 + i;
    if (row < N_NODES) {
      float4 o = make_float4(acc[i][0], acc[i][1], acc[i][2], acc[i][3]);
      *(float4*)&hbuf[(size_t)row * HC + jt + tc * 4] = o;
    }
  }

  float4 asw = *(const float4*)&a_s[head * HID + tc * 4];
  float4 adw = *(const float4*)&a_d[head * HID + tc * 4];
#pragma unroll
  for (int i = 0; i < 4; i++) {
    float ps = acc[i][0] * asw.x + acc[i][1] * asw.y + acc[i][2] * asw.z + acc[i][3] * asw.w;
    float pd = acc[i][0] * adw.x + acc[i][1] * adw.y + acc[i][2] * adw.z + acc[i][3] * adw.w;
#pragma unroll
    for (int m = 1; m < 16; m <<= 1) {
      ps += __shfl_xor(ps, m, 64);
      pd += __shfl_xor(pd, m, 64);
    }
    if (tc == 0) {
      int row = mt * 64 + tr * 4 + i;
      if (row < N_NODES) {
        als[row * HEADS + head] = ps;
        ald[row * HEADS + head] = pd;
      }
    }
  }
}

// ---------------- per-destination softmax + aggregate (one wave per node) ----------------

template <bool RELU>
__global__ __launch_bounds__(256) void agg_kernel(
    const float* __restrict__ hbuf, const float* __restrict__ als,
    const float* __restrict__ ald, const int* __restrict__ rowptr,
    const int* __restrict__ csr_src, const float* __restrict__ bias,
    float* __restrict__ out) {
  int wave = threadIdx.x >> 6;
  int lane = threadIdx.x & 63;
  int v = blockIdx.x * 4 + wave;
  if (v >= N_NODES) return;
  int head = lane >> 4;
  float myald = ald[v * HEADS + head];
  int beg = rowptr[v], end = rowptr[v + 1];

  float m = -1e30f;
  for (int i = beg; i < end; i++) {
    int s = csr_src[i];
    float sc = als[s * HEADS + head] + myald;
    sc = sc > 0.f ? sc : SLOPE * sc;
    m = fmaxf(m, sc);
  }
  float den = 0.f;
  float4 acc = make_float4(0.f, 0.f, 0.f, 0.f);
  for (int i = beg; i < end; i++) {
    int s = csr_src[i];
    float sc = als[s * HEADS + head] + myald;
    sc = sc > 0.f ? sc : SLOPE * sc;
    float ex = expf(sc - m);
    den += ex;
    float4 hv = *(const float4*)&hbuf[(size_t)s * HC + lane * 4];
    acc.x += hv.x * ex; acc.y += hv.y * ex; acc.z += hv.z * ex; acc.w += hv.w * ex;
  }
  float inv = 1.0f / (den + 1e-16f);
  float4 bv = *(const float4*)&bias[lane * 4];
  float4 o;
  o.x = acc.x * inv + bv.x;
  o.y = acc.y * inv + bv.y;
  o.z = acc.z * inv + bv.z;
  o.w = acc.w * inv + bv.w;
  if (RELU) {
    o.x = fmaxf(o.x, 0.f); o.y = fmaxf(o.y, 0.f);
    o.z = fmaxf(o.z, 0.f); o.w = fmaxf(o.w, 0.f);
  }
  *(float4*)&out[(size_t)v * HC + lane * 4] = o;
}

// ---------------- global mean pool: parallel segmented sum (batch sorted) ----------------

__global__ __launch_bounds__(256) void pool_sum_kernel(const float* __restrict__ abuf,
                                                       const int* __restrict__ batch,
                                                       float* __restrict__ pooled_sum) {
  __shared__ int sb[POOL_CHUNK];
  int c = threadIdx.x;  // column 0..255
  int base = blockIdx.x * POOL_CHUNK;
  int nmax = min(POOL_CHUNK, N_NODES - base);
  if (c < nmax) sb[c] = batch[base + c];
  __syncthreads();
  float acc = 0.f;
  int cur = sb[0];
  for (int n = 0; n < nmax; n++) {
    int g = sb[n];
    if (g != cur) {
      atomicAdd(&pooled_sum[cur * HC + c], acc);
      acc = 0.f;
      cur = g;
    }
    acc += abuf[(size_t)(base + n) * HC + c];
  }
  atomicAdd(&pooled_sum[cur * HC + c], acc);
}

__global__ __launch_bounds__(256) void pool_div_kernel(float* __restrict__ pooled_sum,
                                                       const int* __restrict__ batch) {
  int g = blockIdx.x;
  int c = threadIdx.x;
  // count nodes in graph g via binary search on sorted batch
  int lo = 0, hi = N_NODES;
  while (lo < hi) { int mid = (lo + hi) >> 1; if (batch[mid] < g) lo = mid + 1; else hi = mid; }
  int start = lo;
  hi = N_NODES;
  while (lo < hi) { int mid = (lo + hi) >> 1; if (batch[mid] < g + 1) lo = mid + 1; else hi = mid; }
  int cnt = lo - start;
  pooled_sum[g * HC + c] /= fmaxf((float)cnt, 1.0f);
}

// ---------------- MLP head ----------------

__global__ __launch_bounds__(64) void mlp_kernel(const float* __restrict__ pooled,
                                                 const float* __restrict__ w1,
                                                 const float* __restrict__ b1,
                                                 const float* __restrict__ w2,
                                                 const float* __restrict__ b2,
                                                 float* __restrict__ out) {
  int g = blockIdx.x;
  int j = threadIdx.x;  // 64
  __shared__ float z[HID];
  float acc = b1[j];
  for (int k = 0; k < HC; k++) acc += pooled[g * HC + k] * w1[j * HC + k];
  z[j] = fmaxf(acc, 0.f);
  __syncthreads();
  if (j < NC) {
    float o = b2[j];
    for (int k = 0; k < HID; k++) o += z[k] * w2[j * HID + k];
    out[g * NC + j] = o;
  }
}

// ---------------- launch ----------------

extern "C" void kernel_launch(void* const* d_in, const int* in_sizes, int n_in,
                              void* d_out, int out_size, void* d_ws, size_t ws_size,
                              hipStream_t stream) {
  const float* x    = (const float*)d_in[0];
  const int*   ei   = (const int*)d_in[1];
  const int*   batch= (const int*)d_in[2];
  const float* W1   = (const float*)d_in[3];
  const float* as1  = (const float*)d_in[4];
  const float* ad1  = (const float*)d_in[5];
  const float* b1   = (const float*)d_in[6];
  const float* W2   = (const float*)d_in[7];
  const float* as2  = (const float*)d_in[8];
  const float* ad2  = (const float*)d_in[9];
  const float* b2   = (const float*)d_in[10];
  const float* W3   = (const float*)d_in[11];
  const float* as3  = (const float*)d_in[12];
  const float* ad3  = (const float*)d_in[13];
  const float* b3   = (const float*)d_in[14];
  const float* fc1w = (const float*)d_in[15];
  const float* fc1b = (const float*)d_in[16];
  const float* fc2w = (const float*)d_in[17];
  const float* fc2b = (const float*)d_in[18];
  float* out = (float*)d_out;

  char* ws = (char*)d_ws;
  size_t off = 0;
  float* hbuf   = (float*)(ws + off); off += (size_t)N_NODES * HC * 4;
  float* abuf   = (float*)(ws + off); off += (size_t)N_NODES * HC * 4;
  float* als    = (float*)(ws + off); off += (size_t)N_NODES * HEADS * 4;
  float* ald    = (float*)(ws + off); off += (size_t)N_NODES * HEADS * 4;
  float* pooled = (float*)(ws + off); off += (size_t)G_GRAPHS * HC * 4;
  int*   cnt    = (int*)(ws + off);   off += (size_t)N_NODES * 4;
  int*   cursor = (int*)(ws + off);   off += (size_t)N_NODES * 4;
  int*   csrsrc = (int*)(ws + off);   off += (size_t)ET * 4;
  int*   rowptr = (int*)(ws + off);   off += (size_t)(N_NODES + 1) * 4;

  // --- CSR build ---
  hipMemsetAsync(cnt, 0, (size_t)N_NODES * 4, stream);
  hipMemsetAsync(pooled, 0, (size_t)G_GRAPHS * HC * 4, stream);
  count_kernel<<<(ET + 255) / 256, 256, 0, stream>>>(ei, cnt);
  scan_kernel<<<1, 1024, 0, stream>>>(cnt, rowptr, cursor);
  scatter_kernel<<<(ET + 255) / 256, 256, 0, stream>>>(ei, cursor, csrsrc);

  dim3 gemm_grid((N_NODES + 63) / 64, HEADS);
  int agg_grid = (N_NODES + 3) / 4;

  // --- layer 1 ---
  gemm_al_kernel<IN_F><<<gemm_grid, 256, 0, stream>>>(x, W1, as1, ad1, hbuf, als, ald);
  agg_kernel<true><<<agg_grid, 256, 0, stream>>>(hbuf, als, ald, rowptr, csrsrc, b1, abuf);
  // --- layer 2 ---
  gemm_al_kernel<HC><<<gemm_grid, 256, 0, stream>>>(abuf, W2, as2, ad2, hbuf, als, ald);
  agg_kernel<true><<<agg_grid, 256, 0, stream>>>(hbuf, als, ald, rowptr, csrsrc, b2, abuf);
  // --- layer 3 ---
  gemm_al_kernel<HC><<<gemm_grid, 256, 0, stream>>>(abuf, W3, as3, ad3, hbuf, als, ald);
  agg_kernel<false><<<agg_grid, 256, 0, stream>>>(hbuf, als, ald, rowptr, csrsrc, b3, abuf);

  // --- pool + MLP ---
  pool_sum_kernel<<<(N_NODES + POOL_CHUNK - 1) / POOL_CHUNK, 256, 0, stream>>>(abuf, batch, pooled);
  pool_div_kernel<<<G_GRAPHS, 256, 0, stream>>>(pooled, batch);
  mlp_kernel<<<G_GRAPHS, 64, 0, stream>>>(pooled, fc1w, fc1b, fc2w, fc2b, out);
}

// Round 3
// 807.236 us; speedup vs baseline: 1.5206x; 1.2689x over previous
//
#include <hip/hip_runtime.h>
#include <hip/hip_bf16.h>

#define N_NODES 50000
#define E_EDGES 800000
#define ET (E_EDGES + N_NODES)
#define G_GRAPHS 64
#define IN_F 128
#define HID 64
#define HEADS 4
#define HC (HID * HEADS)
#define NC 2
#define SLOPE 0.2f
#define POOL_CHUNK 128

typedef float f32x4 __attribute__((ext_vector_type(4)));
typedef __bf16 bf16x8 __attribute__((ext_vector_type(8)));
typedef unsigned short us8 __attribute__((ext_vector_type(8)));
typedef unsigned short us4 __attribute__((ext_vector_type(4)));

#define MFMA16(a, b, c) \
  __builtin_amdgcn_mfma_f32_16x16x32_bf16(__builtin_bit_cast(bf16x8, (a)), \
                                          __builtin_bit_cast(bf16x8, (b)), (c), 0, 0, 0)

__device__ inline unsigned short f2bf_rne(float f) {
  unsigned u = __builtin_bit_cast(unsigned, f);
  u += 0x7fffu + ((u >> 16) & 1u);
  return (unsigned short)(u >> 16);
}
__device__ inline float bf2f(unsigned short h) {
  unsigned u = ((unsigned)h) << 16;
  return __builtin_bit_cast(float, u);
}

// ---------------- fp32 -> (bf16 hi, bf16 lo) split ----------------

__global__ __launch_bounds__(256) void split_kernel(const float* __restrict__ in,
                                                    unsigned short* __restrict__ hi,
                                                    unsigned short* __restrict__ lo, int n) {
  int i = (blockIdx.x * blockDim.x + threadIdx.x) * 4;
  if (i >= n) return;
  float4 v = *(const float4*)&in[i];
  us4 h, l;
  float f[4] = {v.x, v.y, v.z, v.w};
#pragma unroll
  for (int j = 0; j < 4; j++) {
    unsigned short hb = f2bf_rne(f[j]);
    h[j] = hb;
    l[j] = f2bf_rne(f[j] - bf2f(hb));
  }
  *(us4*)&hi[i] = h;
  *(us4*)&lo[i] = l;
}

// ---------------- CSR build ----------------

__global__ void count_kernel(const int* __restrict__ ei, int* __restrict__ cnt) {
  int e = blockIdx.x * blockDim.x + threadIdx.x;
  if (e >= ET) return;
  int dst = (e < E_EDGES) ? ei[E_EDGES + e] : (e - E_EDGES);
  atomicAdd(&cnt[dst], 1);
}

__global__ __launch_bounds__(1024) void scan_kernel(const int* __restrict__ cnt,
                                                    int* __restrict__ rowptr,
                                                    int* __restrict__ cursor) {
  __shared__ int wsum[16];
  __shared__ int sh_run;
  int tid = threadIdx.x;
  int wave = tid >> 6;
  int lane = tid & 63;
  if (tid == 0) sh_run = 0;
  __syncthreads();
  for (int base = 0; base < N_NODES; base += 1024) {
    int i = base + tid;
    int v = (i < N_NODES) ? cnt[i] : 0;
    int x = v;
#pragma unroll
    for (int off = 1; off < 64; off <<= 1) {
      int t = __shfl_up(x, off, 64);
      if (lane >= off) x += t;
    }
    if (lane == 63) wsum[wave] = x;
    __syncthreads();
    if (wave == 0 && lane < 16) {
      int y = wsum[lane];
#pragma unroll
      for (int off = 1; off < 16; off <<= 1) {
        int t = __shfl_up(y, off, 16);
        if ((lane & 15) >= off) y += t;
      }
      wsum[lane] = y;
    }
    __syncthreads();
    int run = sh_run;
    int incl = run + x + (wave > 0 ? wsum[wave - 1] : 0);
    if (i < N_NODES) {
      rowptr[i + 1] = incl;
      cursor[i] = incl - v;
      if (i == 0) rowptr[0] = 0;
    }
    __syncthreads();
    if (tid == 0) sh_run = run + wsum[15];
    __syncthreads();
  }
}

__global__ void scatter_kernel(const int* __restrict__ ei, int* __restrict__ cursor,
                               int* __restrict__ csr_src) {
  int e = blockIdx.x * blockDim.x + threadIdx.x;
  if (e >= ET) return;
  int src, dst;
  if (e < E_EDGES) { src = ei[e]; dst = ei[E_EDGES + e]; }
  else { src = e - E_EDGES; dst = src; }
  int pos = atomicAdd(&cursor[dst], 1);
  csr_src[pos] = src;
}

// ---------------- split-bf16 MFMA GEMM: h = A @ W^T  (A = Ahi+Alo, W = Whi+Wlo) ----------------
// BM=64 rows, BN=256 (all 4 heads), BK=32. 4 waves; wave w = head w, 64x64 sub-tile.
// LDS layout: chunks of 8 bf16 indexed [kgroup][row] -> 16B-aligned, bank-balanced.

template <int K>
__global__ __launch_bounds__(256) void mfma_gemm_kernel(
    const unsigned short* __restrict__ Ahi, const unsigned short* __restrict__ Alo,
    const unsigned short* __restrict__ Whi, const unsigned short* __restrict__ Wlo,
    const float* __restrict__ a_s, const float* __restrict__ a_d,
    float* __restrict__ hbuf, float* __restrict__ als, float* __restrict__ ald) {
  __shared__ unsigned short As[2][4 * 64 * 8];    // [hi/lo][(kg*64+row)*8]
  __shared__ unsigned short Bs[2][4 * 256 * 8];   // [hi/lo][(kg*256+n)*8]

  int t = threadIdx.x;
  int mt = blockIdx.x;
  int w = t >> 6, lane = t & 63, lr = lane & 15, kg = lane >> 4;
  int arow = t >> 2, akg = t & 3;   // staging coords

  f32x4 acc[4][4];
#pragma unroll
  for (int m = 0; m < 4; m++)
#pragma unroll
    for (int nf = 0; nf < 4; nf++) {
      f32x4 z = {0.f, 0.f, 0.f, 0.f};
      acc[m][nf] = z;
    }

  int agrow = mt * 64 + arow;
  bool avalid = agrow < N_NODES;

  for (int k0 = 0; k0 < K; k0 += 32) {
    // issue global loads (overlap previous compute)
    us8 va0, va1;
    if (avalid) {
      va0 = *(const us8*)&Ahi[(size_t)agrow * K + k0 + akg * 8];
      va1 = *(const us8*)&Alo[(size_t)agrow * K + k0 + akg * 8];
    } else {
      us8 z = {0, 0, 0, 0, 0, 0, 0, 0};
      va0 = z; va1 = z;
    }
    us8 vb0[4], vb1[4];
#pragma unroll
    for (int c = 0; c < 4; c++) {
      int n = arow + 64 * c;
      vb0[c] = *(const us8*)&Whi[(size_t)n * K + k0 + akg * 8];
      vb1[c] = *(const us8*)&Wlo[(size_t)n * K + k0 + akg * 8];
    }
    __syncthreads();
    *(us8*)&As[0][(akg * 64 + arow) * 8] = va0;
    *(us8*)&As[1][(akg * 64 + arow) * 8] = va1;
#pragma unroll
    for (int c = 0; c < 4; c++) {
      int n = arow + 64 * c;
      *(us8*)&Bs[0][(akg * 256 + n) * 8] = vb0[c];
      *(us8*)&Bs[1][(akg * 256 + n) * 8] = vb1[c];
    }
    __syncthreads();

    us8 bh[4], bl[4];
#pragma unroll
    for (int nf = 0; nf < 4; nf++) {
      int n = w * 64 + nf * 16 + lr;
      bh[nf] = *(us8*)&Bs[0][(kg * 256 + n) * 8];
      bl[nf] = *(us8*)&Bs[1][(kg * 256 + n) * 8];
    }
#pragma unroll
    for (int m = 0; m < 4; m++) {
      int row = m * 16 + lr;
      us8 ah = *(us8*)&As[0][(kg * 64 + row) * 8];
      us8 al = *(us8*)&As[1][(kg * 64 + row) * 8];
#pragma unroll
      for (int nf = 0; nf < 4; nf++) {
        acc[m][nf] = MFMA16(ah, bh[nf], acc[m][nf]);
        acc[m][nf] = MFMA16(ah, bl[nf], acc[m][nf]);
        acc[m][nf] = MFMA16(al, bh[nf], acc[m][nf]);
      }
    }
  }

  // epilogue: store h (fp32) + reduce als/ald for head w.
  // C layout: col = nf*16 + lr, row = m*16 + kg*4 + r
  int head = w;
  float asv[4], adv[4];
#pragma unroll
  for (int nf = 0; nf < 4; nf++) {
    asv[nf] = a_s[head * HID + nf * 16 + lr];
    adv[nf] = a_d[head * HID + nf * 16 + lr];
  }
#pragma unroll
  for (int m = 0; m < 4; m++) {
#pragma unroll
    for (int r = 0; r < 4; r++) {
      int grow = mt * 64 + m * 16 + kg * 4 + r;
      float ps = 0.f, pd = 0.f;
#pragma unroll
      for (int nf = 0; nf < 4; nf++) {
        float v = acc[m][nf][r];
        ps += v * asv[nf];
        pd += v * adv[nf];
        if (grow < N_NODES) hbuf[(size_t)grow * HC + head * 64 + nf * 16 + lr] = v;
      }
#pragma unroll
      for (int msk = 1; msk < 16; msk <<= 1) {
        ps += __shfl_xor(ps, msk, 64);
        pd += __shfl_xor(pd, msk, 64);
      }
      if (lr == 0 && grow < N_NODES) {
        als[grow * HEADS + head] = ps;
        ald[grow * HEADS + head] = pd;
      }
    }
  }
}

// ---------------- per-destination softmax + aggregate (one wave per node) ----------------
// SPLIT=true: write bf16 hi/lo pair (input to next layer's MFMA GEMM)
// SPLIT=false: write fp32 (final layer, feeds pool)

template <bool RELU, bool SPLIT>
__global__ __launch_bounds__(256) void agg_kernel(
    const float* __restrict__ hbuf, const float* __restrict__ als,
    const float* __restrict__ ald, const int* __restrict__ rowptr,
    const int* __restrict__ csr_src, const float* __restrict__ bias,
    float* __restrict__ outf, unsigned short* __restrict__ ohi,
    unsigned short* __restrict__ olo) {
  int wave = threadIdx.x >> 6;
  int lane = threadIdx.x & 63;
  int v = blockIdx.x * 4 + wave;
  if (v >= N_NODES) return;
  int head = lane >> 4;
  float myald = ald[v * HEADS + head];
  int beg = rowptr[v], end = rowptr[v + 1];

  float m = -1e30f;
  for (int i = beg; i < end; i++) {
    int s = csr_src[i];
    float sc = als[s * HEADS + head] + myald;
    sc = sc > 0.f ? sc : SLOPE * sc;
    m = fmaxf(m, sc);
  }
  float den = 0.f;
  float4 acc = make_float4(0.f, 0.f, 0.f, 0.f);
  for (int i = beg; i < end; i++) {
    int s = csr_src[i];
    float sc = als[s * HEADS + head] + myald;
    sc = sc > 0.f ? sc : SLOPE * sc;
    float ex = expf(sc - m);
    den += ex;
    float4 hv = *(const float4*)&hbuf[(size_t)s * HC + lane * 4];
    acc.x += hv.x * ex; acc.y += hv.y * ex; acc.z += hv.z * ex; acc.w += hv.w * ex;
  }
  float inv = 1.0f / (den + 1e-16f);
  float4 bv = *(const float4*)&bias[lane * 4];
  float o[4];
  o[0] = acc.x * inv + bv.x;
  o[1] = acc.y * inv + bv.y;
  o[2] = acc.z * inv + bv.z;
  o[3] = acc.w * inv + bv.w;
  if (RELU) {
#pragma unroll
    for (int j = 0; j < 4; j++) o[j] = fmaxf(o[j], 0.f);
  }
  if (SPLIT) {
    us4 h, l;
#pragma unroll
    for (int j = 0; j < 4; j++) {
      unsigned short hb = f2bf_rne(o[j]);
      h[j] = hb;
      l[j] = f2bf_rne(o[j] - bf2f(hb));
    }
    *(us4*)&ohi[(size_t)v * HC + lane * 4] = h;
    *(us4*)&olo[(size_t)v * HC + lane * 4] = l;
  } else {
    float4 of = make_float4(o[0], o[1], o[2], o[3]);
    *(float4*)&outf[(size_t)v * HC + lane * 4] = of;
  }
}

// ---------------- global mean pool: parallel segmented sum (batch sorted) ----------------

__global__ __launch_bounds__(256) void pool_sum_kernel(const float* __restrict__ abuf,
                                                       const int* __restrict__ batch,
                                                       float* __restrict__ pooled_sum) {
  __shared__ int sb[POOL_CHUNK];
  int c = threadIdx.x;
  int base = blockIdx.x * POOL_CHUNK;
  int nmax = min(POOL_CHUNK, N_NODES - base);
  if (c < nmax) sb[c] = batch[base + c];
  __syncthreads();
  float acc = 0.f;
  int cur = sb[0];
  for (int n = 0; n < nmax; n++) {
    int g = sb[n];
    if (g != cur) {
      atomicAdd(&pooled_sum[cur * HC + c], acc);
      acc = 0.f;
      cur = g;
    }
    acc += abuf[(size_t)(base + n) * HC + c];
  }
  atomicAdd(&pooled_sum[cur * HC + c], acc);
}

__global__ __launch_bounds__(256) void pool_div_kernel(float* __restrict__ pooled_sum,
                                                       const int* __restrict__ batch) {
  int g = blockIdx.x;
  int c = threadIdx.x;
  int lo = 0, hi = N_NODES;
  while (lo < hi) { int mid = (lo + hi) >> 1; if (batch[mid] < g) lo = mid + 1; else hi = mid; }
  int start = lo;
  hi = N_NODES;
  while (lo < hi) { int mid = (lo + hi) >> 1; if (batch[mid] < g + 1) lo = mid + 1; else hi = mid; }
  int cnt = lo - start;
  pooled_sum[g * HC + c] /= fmaxf((float)cnt, 1.0f);
}

// ---------------- MLP head ----------------

__global__ __launch_bounds__(64) void mlp_kernel(const float* __restrict__ pooled,
                                                 const float* __restrict__ w1,
                                                 const float* __restrict__ b1,
                                                 const float* __restrict__ w2,
                                                 const float* __restrict__ b2,
                                                 float* __restrict__ out) {
  int g = blockIdx.x;
  int j = threadIdx.x;
  __shared__ float z[HID];
  float acc = b1[j];
  for (int k = 0; k < HC; k++) acc += pooled[g * HC + k] * w1[j * HC + k];
  z[j] = fmaxf(acc, 0.f);
  __syncthreads();
  if (j < NC) {
    float o = b2[j];
    for (int k = 0; k < HID; k++) o += z[k] * w2[j * HID + k];
    out[g * NC + j] = o;
  }
}

// ---------------- launch ----------------

extern "C" void kernel_launch(void* const* d_in, const int* in_sizes, int n_in,
                              void* d_out, int out_size, void* d_ws, size_t ws_size,
                              hipStream_t stream) {
  const float* x    = (const float*)d_in[0];
  const int*   ei   = (const int*)d_in[1];
  const int*   batch= (const int*)d_in[2];
  const float* W1   = (const float*)d_in[3];
  const float* as1  = (const float*)d_in[4];
  const float* ad1  = (const float*)d_in[5];
  const float* b1   = (const float*)d_in[6];
  const float* W2   = (const float*)d_in[7];
  const float* as2  = (const float*)d_in[8];
  const float* ad2  = (const float*)d_in[9];
  const float* b2   = (const float*)d_in[10];
  const float* W3   = (const float*)d_in[11];
  const float* as3  = (const float*)d_in[12];
  const float* ad3  = (const float*)d_in[13];
  const float* b3   = (const float*)d_in[14];
  const float* fc1w = (const float*)d_in[15];
  const float* fc1b = (const float*)d_in[16];
  const float* fc2w = (const float*)d_in[17];
  const float* fc2b = (const float*)d_in[18];
  float* out = (float*)d_out;

  char* ws = (char*)d_ws;
  size_t off = 0;
  float* hbuf = (float*)(ws + off); off += (size_t)N_NODES * HC * 4;        // 51.2 MB
  // union region: (ahi, alo) bf16 pair for layers 1-2 output, abuf fp32 for layer-3 output
  unsigned short* ahi = (unsigned short*)(ws + off);
  unsigned short* alo = ahi + (size_t)N_NODES * HC;
  float* abuf = (float*)(ws + off); off += (size_t)N_NODES * HC * 4;        // 51.2 MB
  unsigned short* xhi = (unsigned short*)(ws + off); off += (size_t)N_NODES * IN_F * 2;
  unsigned short* xlo = (unsigned short*)(ws + off); off += (size_t)N_NODES * IN_F * 2;
  unsigned short* w1h = (unsigned short*)(ws + off); off += (size_t)HC * IN_F * 2;
  unsigned short* w1l = (unsigned short*)(ws + off); off += (size_t)HC * IN_F * 2;
  unsigned short* w2h = (unsigned short*)(ws + off); off += (size_t)HC * HC * 2;
  unsigned short* w2l = (unsigned short*)(ws + off); off += (size_t)HC * HC * 2;
  unsigned short* w3h = (unsigned short*)(ws + off); off += (size_t)HC * HC * 2;
  unsigned short* w3l = (unsigned short*)(ws + off); off += (size_t)HC * HC * 2;
  float* als    = (float*)(ws + off); off += (size_t)N_NODES * HEADS * 4;
  float* ald    = (float*)(ws + off); off += (size_t)N_NODES * HEADS * 4;
  float* pooled = (float*)(ws + off); off += (size_t)G_GRAPHS * HC * 4;
  int*   cnt    = (int*)(ws + off);   off += (size_t)N_NODES * 4;
  int*   cursor = (int*)(ws + off);   off += (size_t)N_NODES * 4;
  int*   csrsrc = (int*)(ws + off);   off += (size_t)ET * 4;
  int*   rowptr = (int*)(ws + off);   off += (size_t)(N_NODES + 1) * 4;

  // --- splits (independent of CSR) ---
  int nx = N_NODES * IN_F;
  split_kernel<<<(nx / 4 + 255) / 256, 256, 0, stream>>>(x, xhi, xlo, nx);
  split_kernel<<<(HC * IN_F / 4 + 255) / 256, 256, 0, stream>>>(W1, w1h, w1l, HC * IN_F);
  split_kernel<<<(HC * HC / 4 + 255) / 256, 256, 0, stream>>>(W2, w2h, w2l, HC * HC);
  split_kernel<<<(HC * HC / 4 + 255) / 256, 256, 0, stream>>>(W3, w3h, w3l, HC * HC);

  // --- CSR build ---
  hipMemsetAsync(cnt, 0, (size_t)N_NODES * 4, stream);
  hipMemsetAsync(pooled, 0, (size_t)G_GRAPHS * HC * 4, stream);
  count_kernel<<<(ET + 255) / 256, 256, 0, stream>>>(ei, cnt);
  scan_kernel<<<1, 1024, 0, stream>>>(cnt, rowptr, cursor);
  scatter_kernel<<<(ET + 255) / 256, 256, 0, stream>>>(ei, cursor, csrsrc);

  dim3 gemm_grid((N_NODES + 63) / 64);
  int agg_grid = (N_NODES + 3) / 4;

  // --- layer 1 ---
  mfma_gemm_kernel<IN_F><<<gemm_grid, 256, 0, stream>>>(xhi, xlo, w1h, w1l, as1, ad1, hbuf, als, ald);
  agg_kernel<true, true><<<agg_grid, 256, 0, stream>>>(hbuf, als, ald, rowptr, csrsrc, b1, nullptr, ahi, alo);
  // --- layer 2 ---
  mfma_gemm_kernel<HC><<<gemm_grid, 256, 0, stream>>>(ahi, alo, w2h, w2l, as2, ad2, hbuf, als, ald);
  agg_kernel<true, true><<<agg_grid, 256, 0, stream>>>(hbuf, als, ald, rowptr, csrsrc, b2, nullptr, ahi, alo);
  // --- layer 3 ---
  mfma_gemm_kernel<HC><<<gemm_grid, 256, 0, stream>>>(ahi, alo, w3h, w3l, as3, ad3, hbuf, als, ald);
  agg_kernel<false, false><<<agg_grid, 256, 0, stream>>>(hbuf, als, ald, rowptr, csrsrc, b3, abuf, nullptr, nullptr);

  // --- pool + MLP ---
  pool_sum_kernel<<<(N_NODES + POOL_CHUNK - 1) / POOL_CHUNK, 256, 0, stream>>>(abuf, batch, pooled);
  pool_div_kernel<<<G_GRAPHS, 256, 0, stream>>>(pooled, batch);
  mlp_kernel<<<G_GRAPHS, 64, 0, stream>>>(pooled, fc1w, fc1b, fc2w, fc2b, out);
}

// Round 4
// 553.607 us; speedup vs baseline: 2.2172x; 1.4581x over previous
//
#include <hip/hip_runtime.h>
#include <hip/hip_bf16.h>

#define N_NODES 50000
#define E_EDGES 800000
#define ET (E_EDGES + N_NODES)
#define G_GRAPHS 64
#define IN_F 128
#define HID 64
#define HEADS 4
#define HC (HID * HEADS)
#define NC 2
#define SLOPE 0.2f
#define POOL_CHUNK 128
#define L2E 1.4426950408889634f

typedef float f32x4 __attribute__((ext_vector_type(4)));
typedef __bf16 bf16x8 __attribute__((ext_vector_type(8)));
typedef unsigned short us8 __attribute__((ext_vector_type(8)));
typedef unsigned short us4 __attribute__((ext_vector_type(4)));
typedef _Float16 h16x4 __attribute__((ext_vector_type(4)));

#define MFMA16(a, b, c) \
  __builtin_amdgcn_mfma_f32_16x16x32_bf16(__builtin_bit_cast(bf16x8, (a)), \
                                          __builtin_bit_cast(bf16x8, (b)), (c), 0, 0, 0)

__device__ inline unsigned short f2bf_rne(float f) {
  unsigned u = __builtin_bit_cast(unsigned, f);
  u += 0x7fffu + ((u >> 16) & 1u);
  return (unsigned short)(u >> 16);
}
__device__ inline float bf2f(unsigned short h) {
  unsigned u = ((unsigned)h) << 16;
  return __builtin_bit_cast(float, u);
}

// ---------------- fp32 -> (bf16 hi, bf16 lo) split ----------------

__global__ __launch_bounds__(256) void split_kernel(const float* __restrict__ in,
                                                    unsigned short* __restrict__ hi,
                                                    unsigned short* __restrict__ lo, int n) {
  int i = (blockIdx.x * blockDim.x + threadIdx.x) * 4;
  if (i >= n) return;
  float4 v = *(const float4*)&in[i];
  us4 h, l;
  float f[4] = {v.x, v.y, v.z, v.w};
#pragma unroll
  for (int j = 0; j < 4; j++) {
    unsigned short hb = f2bf_rne(f[j]);
    h[j] = hb;
    l[j] = f2bf_rne(f[j] - bf2f(hb));
  }
  *(us4*)&hi[i] = h;
  *(us4*)&lo[i] = l;
}

// ---------------- CSR build ----------------

__global__ void count_kernel(const int* __restrict__ ei, int* __restrict__ cnt) {
  int e = blockIdx.x * blockDim.x + threadIdx.x;
  if (e >= ET) return;
  int dst = (e < E_EDGES) ? ei[E_EDGES + e] : (e - E_EDGES);
  atomicAdd(&cnt[dst], 1);
}

__global__ __launch_bounds__(1024) void scan_kernel(const int* __restrict__ cnt,
                                                    int* __restrict__ rowptr,
                                                    int* __restrict__ cursor) {
  __shared__ int wsum[16];
  __shared__ int sh_run;
  int tid = threadIdx.x;
  int wave = tid >> 6;
  int lane = tid & 63;
  if (tid == 0) sh_run = 0;
  __syncthreads();
  for (int base = 0; base < N_NODES; base += 1024) {
    int i = base + tid;
    int v = (i < N_NODES) ? cnt[i] : 0;
    int x = v;
#pragma unroll
    for (int off = 1; off < 64; off <<= 1) {
      int t = __shfl_up(x, off, 64);
      if (lane >= off) x += t;
    }
    if (lane == 63) wsum[wave] = x;
    __syncthreads();
    if (wave == 0 && lane < 16) {
      int y = wsum[lane];
#pragma unroll
      for (int off = 1; off < 16; off <<= 1) {
        int t = __shfl_up(y, off, 16);
        if ((lane & 15) >= off) y += t;
      }
      wsum[lane] = y;
    }
    __syncthreads();
    int run = sh_run;
    int incl = run + x + (wave > 0 ? wsum[wave - 1] : 0);
    if (i < N_NODES) {
      rowptr[i + 1] = incl;
      cursor[i] = incl - v;
      if (i == 0) rowptr[0] = 0;
    }
    __syncthreads();
    if (tid == 0) sh_run = run + wsum[15];
    __syncthreads();
  }
}

__global__ void scatter_kernel(const int* __restrict__ ei, int* __restrict__ cursor,
                               int* __restrict__ csr_src) {
  int e = blockIdx.x * blockDim.x + threadIdx.x;
  if (e >= ET) return;
  int src, dst;
  if (e < E_EDGES) { src = ei[e]; dst = ei[E_EDGES + e]; }
  else { src = e - E_EDGES; dst = src; }
  int pos = atomicAdd(&cursor[dst], 1);
  csr_src[pos] = src;
}

// ---------------- split-bf16 MFMA GEMM: h = A @ W^T  (A = Ahi+Alo, W = Whi+Wlo) ----------------
// BM=64 rows, BN=256 (all 4 heads), BK=32. 4 waves; wave w = head w, 64x64 sub-tile.
// Writes h as fp16 (gather payload) + fp32 als/ald attention coefficients.

template <int K>
__global__ __launch_bounds__(256) void mfma_gemm_kernel(
    const unsigned short* __restrict__ Ahi, const unsigned short* __restrict__ Alo,
    const unsigned short* __restrict__ Whi, const unsigned short* __restrict__ Wlo,
    const float* __restrict__ a_s, const float* __restrict__ a_d,
    _Float16* __restrict__ hbuf16, float* __restrict__ als, float* __restrict__ ald) {
  __shared__ unsigned short As[2][4 * 64 * 8];    // [hi/lo][(kg*64+row)*8]
  __shared__ unsigned short Bs[2][4 * 256 * 8];   // [hi/lo][(kg*256+n)*8]

  int t = threadIdx.x;
  int mt = blockIdx.x;
  int w = t >> 6, lane = t & 63, lr = lane & 15, kg = lane >> 4;
  int arow = t >> 2, akg = t & 3;

  f32x4 acc[4][4];
#pragma unroll
  for (int m = 0; m < 4; m++)
#pragma unroll
    for (int nf = 0; nf < 4; nf++) {
      f32x4 z = {0.f, 0.f, 0.f, 0.f};
      acc[m][nf] = z;
    }

  int agrow = mt * 64 + arow;
  bool avalid = agrow < N_NODES;

  for (int k0 = 0; k0 < K; k0 += 32) {
    us8 va0, va1;
    if (avalid) {
      va0 = *(const us8*)&Ahi[(size_t)agrow * K + k0 + akg * 8];
      va1 = *(const us8*)&Alo[(size_t)agrow * K + k0 + akg * 8];
    } else {
      us8 z = {0, 0, 0, 0, 0, 0, 0, 0};
      va0 = z; va1 = z;
    }
    us8 vb0[4], vb1[4];
#pragma unroll
    for (int c = 0; c < 4; c++) {
      int n = arow + 64 * c;
      vb0[c] = *(const us8*)&Whi[(size_t)n * K + k0 + akg * 8];
      vb1[c] = *(const us8*)&Wlo[(size_t)n * K + k0 + akg * 8];
    }
    __syncthreads();
    *(us8*)&As[0][(akg * 64 + arow) * 8] = va0;
    *(us8*)&As[1][(akg * 64 + arow) * 8] = va1;
#pragma unroll
    for (int c = 0; c < 4; c++) {
      int n = arow + 64 * c;
      *(us8*)&Bs[0][(akg * 256 + n) * 8] = vb0[c];
      *(us8*)&Bs[1][(akg * 256 + n) * 8] = vb1[c];
    }
    __syncthreads();

    us8 bh[4], bl[4];
#pragma unroll
    for (int nf = 0; nf < 4; nf++) {
      int n = w * 64 + nf * 16 + lr;
      bh[nf] = *(us8*)&Bs[0][(kg * 256 + n) * 8];
      bl[nf] = *(us8*)&Bs[1][(kg * 256 + n) * 8];
    }
#pragma unroll
    for (int m = 0; m < 4; m++) {
      int row = m * 16 + lr;
      us8 ah = *(us8*)&As[0][(kg * 64 + row) * 8];
      us8 al = *(us8*)&As[1][(kg * 64 + row) * 8];
#pragma unroll
      for (int nf = 0; nf < 4; nf++) {
        acc[m][nf] = MFMA16(ah, bh[nf], acc[m][nf]);
        acc[m][nf] = MFMA16(ah, bl[nf], acc[m][nf]);
        acc[m][nf] = MFMA16(al, bh[nf], acc[m][nf]);
      }
    }
  }

  // epilogue: store h (fp16) + reduce als/ald for head w.
  // C layout: col = nf*16 + lr, row = m*16 + kg*4 + r
  int head = w;
  float asv[4], adv[4];
#pragma unroll
  for (int nf = 0; nf < 4; nf++) {
    asv[nf] = a_s[head * HID + nf * 16 + lr];
    adv[nf] = a_d[head * HID + nf * 16 + lr];
  }
#pragma unroll
  for (int m = 0; m < 4; m++) {
#pragma unroll
    for (int r = 0; r < 4; r++) {
      int grow = mt * 64 + m * 16 + kg * 4 + r;
      float ps = 0.f, pd = 0.f;
#pragma unroll
      for (int nf = 0; nf < 4; nf++) {
        float v = acc[m][nf][r];
        ps += v * asv[nf];
        pd += v * adv[nf];
        if (grow < N_NODES)
          hbuf16[(size_t)grow * HC + head * 64 + nf * 16 + lr] = (_Float16)v;
      }
#pragma unroll
      for (int msk = 1; msk < 16; msk <<= 1) {
        ps += __shfl_xor(ps, msk, 64);
        pd += __shfl_xor(pd, msk, 64);
      }
      if (lr == 0 && grow < N_NODES) {
        als[grow * HEADS + head] = ps;
        ald[grow * HEADS + head] = pd;
      }
    }
  }
}

// ---------------- per-destination online-softmax + aggregate (one wave per node) ----------------

template <bool RELU, bool SPLIT>
__global__ __launch_bounds__(256) void agg_kernel(
    const _Float16* __restrict__ hbuf16, const float* __restrict__ als,
    const float* __restrict__ ald, const int* __restrict__ rowptr,
    const int* __restrict__ csr_src, const float* __restrict__ bias,
    float* __restrict__ outf, unsigned short* __restrict__ ohi,
    unsigned short* __restrict__ olo) {
  int wave = threadIdx.x >> 6;
  int lane = threadIdx.x & 63;
  int v = blockIdx.x * 4 + wave;
  if (v >= N_NODES) return;
  int head = lane >> 4;
  float myald = ald[v * HEADS + head];
  int beg = rowptr[v], end = rowptr[v + 1];

  float m = -1e30f, den = 0.f;
  float4 acc = make_float4(0.f, 0.f, 0.f, 0.f);
#pragma unroll 2
  for (int i = beg; i < end; i++) {
    int s = csr_src[i];
    float sc = als[s * HEADS + head] + myald;
    sc = sc > 0.f ? sc : SLOPE * sc;
    float mn = fmaxf(m, sc);
    float scale = __builtin_amdgcn_exp2f((m - mn) * L2E);
    float ex = __builtin_amdgcn_exp2f((sc - mn) * L2E);
    den = den * scale + ex;
    unsigned off = (unsigned)s * HC + (lane << 2);
    h16x4 hv = *(const h16x4*)&hbuf16[off];
    acc.x = acc.x * scale + (float)hv[0] * ex;
    acc.y = acc.y * scale + (float)hv[1] * ex;
    acc.z = acc.z * scale + (float)hv[2] * ex;
    acc.w = acc.w * scale + (float)hv[3] * ex;
    m = mn;
  }
  float inv = 1.0f / (den + 1e-16f);
  float4 bv = *(const float4*)&bias[lane * 4];
  float o[4];
  o[0] = acc.x * inv + bv.x;
  o[1] = acc.y * inv + bv.y;
  o[2] = acc.z * inv + bv.z;
  o[3] = acc.w * inv + bv.w;
  if (RELU) {
#pragma unroll
    for (int j = 0; j < 4; j++) o[j] = fmaxf(o[j], 0.f);
  }
  if (SPLIT) {
    us4 h, l;
#pragma unroll
    for (int j = 0; j < 4; j++) {
      unsigned short hb = f2bf_rne(o[j]);
      h[j] = hb;
      l[j] = f2bf_rne(o[j] - bf2f(hb));
    }
    *(us4*)&ohi[(size_t)v * HC + lane * 4] = h;
    *(us4*)&olo[(size_t)v * HC + lane * 4] = l;
  } else {
    float4 of = make_float4(o[0], o[1], o[2], o[3]);
    *(float4*)&outf[(size_t)v * HC + lane * 4] = of;
  }
}

// ---------------- global mean pool: parallel segmented sum (batch sorted) ----------------

__global__ __launch_bounds__(256) void pool_sum_kernel(const float* __restrict__ abuf,
                                                       const int* __restrict__ batch,
                                                       float* __restrict__ pooled_sum) {
  __shared__ int sb[POOL_CHUNK];
  int c = threadIdx.x;
  int base = blockIdx.x * POOL_CHUNK;
  int nmax = min(POOL_CHUNK, N_NODES - base);
  if (c < nmax) sb[c] = batch[base + c];
  __syncthreads();
  float acc = 0.f;
  int cur = sb[0];
  for (int n = 0; n < nmax; n++) {
    int g = sb[n];
    if (g != cur) {
      atomicAdd(&pooled_sum[cur * HC + c], acc);
      acc = 0.f;
      cur = g;
    }
    acc += abuf[(size_t)(base + n) * HC + c];
  }
  atomicAdd(&pooled_sum[cur * HC + c], acc);
}

__global__ __launch_bounds__(256) void pool_div_kernel(float* __restrict__ pooled_sum,
                                                       const int* __restrict__ batch) {
  int g = blockIdx.x;
  int c = threadIdx.x;
  int lo = 0, hi = N_NODES;
  while (lo < hi) { int mid = (lo + hi) >> 1; if (batch[mid] < g) lo = mid + 1; else hi = mid; }
  int start = lo;
  hi = N_NODES;
  while (lo < hi) { int mid = (lo + hi) >> 1; if (batch[mid] < g + 1) lo = mid + 1; else hi = mid; }
  int cnt = lo - start;
  pooled_sum[g * HC + c] /= fmaxf((float)cnt, 1.0f);
}

// ---------------- MLP head ----------------

__global__ __launch_bounds__(64) void mlp_kernel(const float* __restrict__ pooled,
                                                 const float* __restrict__ w1,
                                                 const float* __restrict__ b1,
                                                 const float* __restrict__ w2,
                                                 const float* __restrict__ b2,
                                                 float* __restrict__ out) {
  int g = blockIdx.x;
  int j = threadIdx.x;
  __shared__ float z[HID];
  float acc = b1[j];
  for (int k = 0; k < HC; k++) acc += pooled[g * HC + k] * w1[j * HC + k];
  z[j] = fmaxf(acc, 0.f);
  __syncthreads();
  if (j < NC) {
    float o = b2[j];
    for (int k = 0; k < HID; k++) o += z[k] * w2[j * HID + k];
    out[g * NC + j] = o;
  }
}

// ---------------- launch ----------------

extern "C" void kernel_launch(void* const* d_in, const int* in_sizes, int n_in,
                              void* d_out, int out_size, void* d_ws, size_t ws_size,
                              hipStream_t stream) {
  const float* x    = (const float*)d_in[0];
  const int*   ei   = (const int*)d_in[1];
  const int*   batch= (const int*)d_in[2];
  const float* W1   = (const float*)d_in[3];
  const float* as1  = (const float*)d_in[4];
  const float* ad1  = (const float*)d_in[5];
  const float* b1   = (const float*)d_in[6];
  const float* W2   = (const float*)d_in[7];
  const float* as2  = (const float*)d_in[8];
  const float* ad2  = (const float*)d_in[9];
  const float* b2   = (const float*)d_in[10];
  const float* W3   = (const float*)d_in[11];
  const float* as3  = (const float*)d_in[12];
  const float* ad3  = (const float*)d_in[13];
  const float* b3   = (const float*)d_in[14];
  const float* fc1w = (const float*)d_in[15];
  const float* fc1b = (const float*)d_in[16];
  const float* fc2w = (const float*)d_in[17];
  const float* fc2b = (const float*)d_in[18];
  float* out = (float*)d_out;

  char* ws = (char*)d_ws;
  size_t off = 0;
  _Float16* hbuf16 = (_Float16*)(ws + off); off += (size_t)N_NODES * HC * 2;  // 25.6 MB
  // union region: (ahi, alo) bf16 pair for layers 1-2 output, abuf fp32 for layer-3 output
  unsigned short* ahi = (unsigned short*)(ws + off);
  unsigned short* alo = ahi + (size_t)N_NODES * HC;
  float* abuf = (float*)(ws + off); off += (size_t)N_NODES * HC * 4;          // 51.2 MB
  unsigned short* xhi = (unsigned short*)(ws + off); off += (size_t)N_NODES * IN_F * 2;
  unsigned short* xlo = (unsigned short*)(ws + off); off += (size_t)N_NODES * IN_F * 2;
  unsigned short* w1h = (unsigned short*)(ws + off); off += (size_t)HC * IN_F * 2;
  unsigned short* w1l = (unsigned short*)(ws + off); off += (size_t)HC * IN_F * 2;
  unsigned short* w2h = (unsigned short*)(ws + off); off += (size_t)HC * HC * 2;
  unsigned short* w2l = (unsigned short*)(ws + off); off += (size_t)HC * HC * 2;
  unsigned short* w3h = (unsigned short*)(ws + off); off += (size_t)HC * HC * 2;
  unsigned short* w3l = (unsigned short*)(ws + off); off += (size_t)HC * HC * 2;
  float* als    = (float*)(ws + off); off += (size_t)N_NODES * HEADS * 4;
  float* ald    = (float*)(ws + off); off += (size_t)N_NODES * HEADS * 4;
  float* pooled = (float*)(ws + off); off += (size_t)G_GRAPHS * HC * 4;
  int*   cnt    = (int*)(ws + off);   off += (size_t)N_NODES * 4;
  int*   cursor = (int*)(ws + off);   off += (size_t)N_NODES * 4;
  int*   csrsrc = (int*)(ws + off);   off += (size_t)ET * 4;
  int*   rowptr = (int*)(ws + off);   off += (size_t)(N_NODES + 1) * 4;

  // --- splits (independent of CSR) ---
  int nx = N_NODES * IN_F;
  split_kernel<<<(nx / 4 + 255) / 256, 256, 0, stream>>>(x, xhi, xlo, nx);
  split_kernel<<<(HC * IN_F / 4 + 255) / 256, 256, 0, stream>>>(W1, w1h, w1l, HC * IN_F);
  split_kernel<<<(HC * HC / 4 + 255) / 256, 256, 0, stream>>>(W2, w2h, w2l, HC * HC);
  split_kernel<<<(HC * HC / 4 + 255) / 256, 256, 0, stream>>>(W3, w3h, w3l, HC * HC);

  // --- CSR build ---
  hipMemsetAsync(cnt, 0, (size_t)N_NODES * 4, stream);
  hipMemsetAsync(pooled, 0, (size_t)G_GRAPHS * HC * 4, stream);
  count_kernel<<<(ET + 255) / 256, 256, 0, stream>>>(ei, cnt);
  scan_kernel<<<1, 1024, 0, stream>>>(cnt, rowptr, cursor);
  scatter_kernel<<<(ET + 255) / 256, 256, 0, stream>>>(ei, cursor, csrsrc);

  dim3 gemm_grid((N_NODES + 63) / 64);
  int agg_grid = (N_NODES + 3) / 4;

  // --- layer 1 ---
  mfma_gemm_kernel<IN_F><<<gemm_grid, 256, 0, stream>>>(xhi, xlo, w1h, w1l, as1, ad1, hbuf16, als, ald);
  agg_kernel<true, true><<<agg_grid, 256, 0, stream>>>(hbuf16, als, ald, rowptr, csrsrc, b1, nullptr, ahi, alo);
  // --- layer 2 ---
  mfma_gemm_kernel<HC><<<gemm_grid, 256, 0, stream>>>(ahi, alo, w2h, w2l, as2, ad2, hbuf16, als, ald);
  agg_kernel<true, true><<<agg_grid, 256, 0, stream>>>(hbuf16, als, ald, rowptr, csrsrc, b2, nullptr, ahi, alo);
  // --- layer 3 ---
  mfma_gemm_kernel<HC><<<gemm_grid, 256, 0, stream>>>(ahi, alo, w3h, w3l, as3, ad3, hbuf16, als, ald);
  agg_kernel<false, false><<<agg_grid, 256, 0, stream>>>(hbuf16, als, ald, rowptr, csrsrc, b3, abuf, nullptr, nullptr);

  // --- pool + MLP ---
  pool_sum_kernel<<<(N_NODES + POOL_CHUNK - 1) / POOL_CHUNK, 256, 0, stream>>>(abuf, batch, pooled);
  pool_div_kernel<<<G_GRAPHS, 256, 0, stream>>>(pooled, batch);
  mlp_kernel<<<G_GRAPHS, 64, 0, stream>>>(pooled, fc1w, fc1b, fc2w, fc2b, out);
}

// Round 5
// 532.951 us; speedup vs baseline: 2.3031x; 1.0388x over previous
//
#include <hip/hip_runtime.h>
#include <hip/hip_bf16.h>

#define N_NODES 50000
#define E_EDGES 800000
#define ET (E_EDGES + N_NODES)
#define G_GRAPHS 64
#define IN_F 128
#define HID 64
#define HEADS 4
#define HC (HID * HEADS)
#define NC 2
#define SLOPE 0.2f
#define L2E 1.4426950408889634f

typedef float f32x4 __attribute__((ext_vector_type(4)));
typedef __bf16 bf16x8 __attribute__((ext_vector_type(8)));
typedef unsigned short us8 __attribute__((ext_vector_type(8)));
typedef unsigned short us4 __attribute__((ext_vector_type(4)));
typedef _Float16 h16x4 __attribute__((ext_vector_type(4)));

#define MFMA16(a, b, c) \
  __builtin_amdgcn_mfma_f32_16x16x32_bf16(__builtin_bit_cast(bf16x8, (a)), \
                                          __builtin_bit_cast(bf16x8, (b)), (c), 0, 0, 0)

__device__ inline unsigned short f2bf_rne(float f) {
  unsigned u = __builtin_bit_cast(unsigned, f);
  u += 0x7fffu + ((u >> 16) & 1u);
  return (unsigned short)(u >> 16);
}
__device__ inline float bf2f(unsigned short h) {
  unsigned u = ((unsigned)h) << 16;
  return __builtin_bit_cast(float, u);
}

// ---------------- fp32 -> (bf16 hi, bf16 lo) split ----------------

__global__ __launch_bounds__(256) void split_kernel(const float* __restrict__ in,
                                                    unsigned short* __restrict__ hi,
                                                    unsigned short* __restrict__ lo, int n) {
  int i = (blockIdx.x * blockDim.x + threadIdx.x) * 4;
  if (i >= n) return;
  float4 v = *(const float4*)&in[i];
  us4 h, l;
  float f[4] = {v.x, v.y, v.z, v.w};
#pragma unroll
  for (int j = 0; j < 4; j++) {
    unsigned short hb = f2bf_rne(f[j]);
    h[j] = hb;
    l[j] = f2bf_rne(f[j] - bf2f(hb));
  }
  *(us4*)&hi[i] = h;
  *(us4*)&lo[i] = l;
}

// ---------------- CSR build ----------------

__global__ void count_kernel(const int* __restrict__ ei, int* __restrict__ cnt) {
  int e = blockIdx.x * blockDim.x + threadIdx.x;
  if (e >= ET) return;
  int dst = (e < E_EDGES) ? ei[E_EDGES + e] : (e - E_EDGES);
  atomicAdd(&cnt[dst], 1);
}

__global__ __launch_bounds__(1024) void scan_kernel(const int* __restrict__ cnt,
                                                    int* __restrict__ rowptr,
                                                    int* __restrict__ cursor) {
  __shared__ int wsum[16];
  __shared__ int sh_run;
  int tid = threadIdx.x;
  int wave = tid >> 6;
  int lane = tid & 63;
  if (tid == 0) sh_run = 0;
  __syncthreads();
  for (int base = 0; base < N_NODES; base += 1024) {
    int i = base + tid;
    int v = (i < N_NODES) ? cnt[i] : 0;
    int x = v;
#pragma unroll
    for (int off = 1; off < 64; off <<= 1) {
      int t = __shfl_up(x, off, 64);
      if (lane >= off) x += t;
    }
    if (lane == 63) wsum[wave] = x;
    __syncthreads();
    if (wave == 0 && lane < 16) {
      int y = wsum[lane];
#pragma unroll
      for (int off = 1; off < 16; off <<= 1) {
        int t = __shfl_up(y, off, 16);
        if ((lane & 15) >= off) y += t;
      }
      wsum[lane] = y;
    }
    __syncthreads();
    int run = sh_run;
    int incl = run + x + (wave > 0 ? wsum[wave - 1] : 0);
    if (i < N_NODES) {
      rowptr[i + 1] = incl;
      cursor[i] = incl - v;
      if (i == 0) rowptr[0] = 0;
    }
    __syncthreads();
    if (tid == 0) sh_run = run + wsum[15];
    __syncthreads();
  }
}

__global__ void scatter_kernel(const int* __restrict__ ei, int* __restrict__ cursor,
                               int* __restrict__ csr_src) {
  int e = blockIdx.x * blockDim.x + threadIdx.x;
  if (e >= ET) return;
  int src, dst;
  if (e < E_EDGES) { src = ei[e]; dst = ei[E_EDGES + e]; }
  else { src = e - E_EDGES; dst = src; }
  int pos = atomicAdd(&cursor[dst], 1);
  csr_src[pos] = src;
}

// ---------------- split-bf16 MFMA GEMM: h = A @ W^T ----------------
// BM=128 rows, BN=256 (all 4 heads), BK=32. 4 waves; wave w = head w, 128x64 sub-tile.
// Writes h as fp16 + (log2e-scaled) fp32 als/ald attention coefficients.

template <int K>
__global__ __launch_bounds__(256) void mfma_gemm_kernel(
    const unsigned short* __restrict__ Ahi, const unsigned short* __restrict__ Alo,
    const unsigned short* __restrict__ Whi, const unsigned short* __restrict__ Wlo,
    const float* __restrict__ a_s, const float* __restrict__ a_d,
    _Float16* __restrict__ hbuf16, float* __restrict__ als, float* __restrict__ ald) {
  __shared__ unsigned short As[2][4 * 128 * 8];   // 16 KB
  __shared__ unsigned short Bs[2][4 * 256 * 8];   // 32 KB

  int t = threadIdx.x;
  int mt = blockIdx.x;
  int w = t >> 6, lane = t & 63, lr = lane & 15, kg = lane >> 4;
  int srow = t >> 2, skg = t & 3;   // staging coords

  f32x4 acc[8][4];
#pragma unroll
  for (int m = 0; m < 8; m++)
#pragma unroll
    for (int nf = 0; nf < 4; nf++) {
      f32x4 z = {0.f, 0.f, 0.f, 0.f};
      acc[m][nf] = z;
    }

  for (int k0 = 0; k0 < K; k0 += 32) {
    // issue global loads (overlap previous compute)
    us8 va0[2], va1[2];
#pragma unroll
    for (int i = 0; i < 2; i++) {
      int agrow = mt * 128 + srow + 64 * i;
      if (agrow < N_NODES) {
        va0[i] = *(const us8*)&Ahi[(size_t)agrow * K + k0 + skg * 8];
        va1[i] = *(const us8*)&Alo[(size_t)agrow * K + k0 + skg * 8];
      } else {
        us8 z = {0, 0, 0, 0, 0, 0, 0, 0};
        va0[i] = z; va1[i] = z;
      }
    }
    us8 vb0[4], vb1[4];
#pragma unroll
    for (int c = 0; c < 4; c++) {
      int n = srow + 64 * c;
      vb0[c] = *(const us8*)&Whi[(size_t)n * K + k0 + skg * 8];
      vb1[c] = *(const us8*)&Wlo[(size_t)n * K + k0 + skg * 8];
    }
    __syncthreads();
#pragma unroll
    for (int i = 0; i < 2; i++) {
      int row = srow + 64 * i;
      *(us8*)&As[0][(skg * 128 + row) * 8] = va0[i];
      *(us8*)&As[1][(skg * 128 + row) * 8] = va1[i];
    }
#pragma unroll
    for (int c = 0; c < 4; c++) {
      int n = srow + 64 * c;
      *(us8*)&Bs[0][(skg * 256 + n) * 8] = vb0[c];
      *(us8*)&Bs[1][(skg * 256 + n) * 8] = vb1[c];
    }
    __syncthreads();

    us8 bh[4], bl[4];
#pragma unroll
    for (int nf = 0; nf < 4; nf++) {
      int n = w * 64 + nf * 16 + lr;
      bh[nf] = *(us8*)&Bs[0][(kg * 256 + n) * 8];
      bl[nf] = *(us8*)&Bs[1][(kg * 256 + n) * 8];
    }
#pragma unroll
    for (int m = 0; m < 8; m++) {
      int row = m * 16 + lr;
      us8 ah = *(us8*)&As[0][(kg * 128 + row) * 8];
      us8 al = *(us8*)&As[1][(kg * 128 + row) * 8];
#pragma unroll
      for (int nf = 0; nf < 4; nf++) {
        acc[m][nf] = MFMA16(ah, bh[nf], acc[m][nf]);
        acc[m][nf] = MFMA16(ah, bl[nf], acc[m][nf]);
        acc[m][nf] = MFMA16(al, bh[nf], acc[m][nf]);
      }
    }
  }

  // epilogue: store h (fp16) + reduce als/ald (scaled by log2e) for head w.
  // C layout: col = nf*16 + lr, row = m*16 + kg*4 + r
  int head = w;
  float asv[4], adv[4];
#pragma unroll
  for (int nf = 0; nf < 4; nf++) {
    asv[nf] = a_s[head * HID + nf * 16 + lr];
    adv[nf] = a_d[head * HID + nf * 16 + lr];
  }
#pragma unroll
  for (int m = 0; m < 8; m++) {
#pragma unroll
    for (int r = 0; r < 4; r++) {
      int grow = mt * 128 + m * 16 + kg * 4 + r;
      float ps = 0.f, pd = 0.f;
#pragma unroll
      for (int nf = 0; nf < 4; nf++) {
        float v = acc[m][nf][r];
        ps += v * asv[nf];
        pd += v * adv[nf];
        if (grow < N_NODES)
          hbuf16[(size_t)grow * HC + head * 64 + nf * 16 + lr] = (_Float16)v;
      }
#pragma unroll
      for (int msk = 1; msk < 16; msk <<= 1) {
        ps += __shfl_xor(ps, msk, 64);
        pd += __shfl_xor(pd, msk, 64);
      }
      if (lr == 0 && grow < N_NODES) {
        als[grow * HEADS + head] = ps * L2E;
        ald[grow * HEADS + head] = pd * L2E;
      }
    }
  }
}

// ---------------- per-destination softmax + aggregate (one wave per node) ----------------
// No max-subtraction: scores bounded (|sc| <~ 10 << 88 overflow), alpha identical.
// MODE 0: relu + bf16 hi/lo split output (layers 1,2)
// MODE 1: + bias, no relu, fused mean-pool atomic accumulation (layer 3)
// Grid is exactly N_NODES/4 blocks (50000 % 4 == 0): no early returns.

template <int MODE>
__global__ __launch_bounds__(256) void agg_kernel(
    const _Float16* __restrict__ hbuf16, const float* __restrict__ alsE,
    const float* __restrict__ aldE, const int* __restrict__ rowptr,
    const int* __restrict__ csr_src, const float* __restrict__ bias,
    unsigned short* __restrict__ ohi, unsigned short* __restrict__ olo,
    float* __restrict__ pooled, const int* __restrict__ batch) {
  int wave = threadIdx.x >> 6;
  int lane = threadIdx.x & 63;
  int v = blockIdx.x * 4 + wave;
  int head = lane >> 4;
  float myald = aldE[(unsigned)v * HEADS + head];
  int beg = rowptr[v], end = rowptr[v + 1];

  float den = 0.f;
  f32x4 acc = {0.f, 0.f, 0.f, 0.f};
  const _Float16* hp = hbuf16 + (lane << 2);
#pragma unroll 4
  for (int i = beg; i < end; i++) {
    int s = csr_src[i];
    float a = alsE[(unsigned)s * HEADS + head] + myald;
    a = fmaxf(a, SLOPE * a);                    // leaky (log2e-scaled domain)
    float ex = __builtin_amdgcn_exp2f(a);
    den += ex;
    h16x4 hv = *(const h16x4*)(hp + ((unsigned)s << 8));
    acc[0] += (float)hv[0] * ex;
    acc[1] += (float)hv[1] * ex;
    acc[2] += (float)hv[2] * ex;
    acc[3] += (float)hv[3] * ex;
  }
  float inv = 1.0f / (den + 1e-16f);
  float4 bv = *(const float4*)&bias[lane * 4];
  float o[4];
  o[0] = acc[0] * inv + bv.x;
  o[1] = acc[1] * inv + bv.y;
  o[2] = acc[2] * inv + bv.z;
  o[3] = acc[3] * inv + bv.w;

  if (MODE == 0) {
    us4 h, l;
#pragma unroll
    for (int j = 0; j < 4; j++) {
      o[j] = fmaxf(o[j], 0.f);
      unsigned short hb = f2bf_rne(o[j]);
      h[j] = hb;
      l[j] = f2bf_rne(o[j] - bf2f(hb));
    }
    *(us4*)&ohi[(size_t)v * HC + lane * 4] = h;
    *(us4*)&olo[(size_t)v * HC + lane * 4] = l;
  } else {
    __shared__ float pacc[4][HC];
    __shared__ int pg[4];
    f32x4 ov = {o[0], o[1], o[2], o[3]};
    *(f32x4*)&pacc[wave][lane * 4] = ov;
    if (lane == 0) pg[wave] = batch[v];
    __syncthreads();
    int c = threadIdx.x;
    int g0 = pg[0], g1 = pg[1], g2 = pg[2], g3 = pg[3];
    if (g0 == g1 && g1 == g2 && g2 == g3) {
      atomicAdd(&pooled[g0 * HC + c], pacc[0][c] + pacc[1][c] + pacc[2][c] + pacc[3][c]);
    } else {
      atomicAdd(&pooled[g0 * HC + c], pacc[0][c]);
      atomicAdd(&pooled[g1 * HC + c], pacc[1][c]);
      atomicAdd(&pooled[g2 * HC + c], pacc[2][c]);
      atomicAdd(&pooled[g3 * HC + c], pacc[3][c]);
    }
  }
}

// ---------------- pool divide ----------------

__global__ __launch_bounds__(256) void pool_div_kernel(float* __restrict__ pooled_sum,
                                                       const int* __restrict__ batch) {
  int g = blockIdx.x;
  int c = threadIdx.x;
  int lo = 0, hi = N_NODES;
  while (lo < hi) { int mid = (lo + hi) >> 1; if (batch[mid] < g) lo = mid + 1; else hi = mid; }
  int start = lo;
  hi = N_NODES;
  while (lo < hi) { int mid = (lo + hi) >> 1; if (batch[mid] < g + 1) lo = mid + 1; else hi = mid; }
  int cnt = lo - start;
  pooled_sum[g * HC + c] /= fmaxf((float)cnt, 1.0f);
}

// ---------------- MLP head ----------------

__global__ __launch_bounds__(64) void mlp_kernel(const float* __restrict__ pooled,
                                                 const float* __restrict__ w1,
                                                 const float* __restrict__ b1,
                                                 const float* __restrict__ w2,
                                                 const float* __restrict__ b2,
                                                 float* __restrict__ out) {
  int g = blockIdx.x;
  int j = threadIdx.x;
  __shared__ float z[HID];
  float acc = b1[j];
  for (int k = 0; k < HC; k++) acc += pooled[g * HC + k] * w1[j * HC + k];
  z[j] = fmaxf(acc, 0.f);
  __syncthreads();
  if (j < NC) {
    float o = b2[j];
    for (int k = 0; k < HID; k++) o += z[k] * w2[j * HID + k];
    out[g * NC + j] = o;
  }
}

// ---------------- launch ----------------

extern "C" void kernel_launch(void* const* d_in, const int* in_sizes, int n_in,
                              void* d_out, int out_size, void* d_ws, size_t ws_size,
                              hipStream_t stream) {
  const float* x    = (const float*)d_in[0];
  const int*   ei   = (const int*)d_in[1];
  const int*   batch= (const int*)d_in[2];
  const float* W1   = (const float*)d_in[3];
  const float* as1  = (const float*)d_in[4];
  const float* ad1  = (const float*)d_in[5];
  const float* b1   = (const float*)d_in[6];
  const float* W2   = (const float*)d_in[7];
  const float* as2  = (const float*)d_in[8];
  const float* ad2  = (const float*)d_in[9];
  const float* b2   = (const float*)d_in[10];
  const float* W3   = (const float*)d_in[11];
  const float* as3  = (const float*)d_in[12];
  const float* ad3  = (const float*)d_in[13];
  const float* b3   = (const float*)d_in[14];
  const float* fc1w = (const float*)d_in[15];
  const float* fc1b = (const float*)d_in[16];
  const float* fc2w = (const float*)d_in[17];
  const float* fc2b = (const float*)d_in[18];
  float* out = (float*)d_out;

  char* ws = (char*)d_ws;
  size_t off = 0;
  _Float16* hbuf16 = (_Float16*)(ws + off); off += (size_t)N_NODES * HC * 2;  // 25.6 MB
  unsigned short* ahi = (unsigned short*)(ws + off); off += (size_t)N_NODES * HC * 2;
  unsigned short* alo = (unsigned short*)(ws + off); off += (size_t)N_NODES * HC * 2;
  unsigned short* xhi = (unsigned short*)(ws + off); off += (size_t)N_NODES * IN_F * 2;
  unsigned short* xlo = (unsigned short*)(ws + off); off += (size_t)N_NODES * IN_F * 2;
  unsigned short* w1h = (unsigned short*)(ws + off); off += (size_t)HC * IN_F * 2;
  unsigned short* w1l = (unsigned short*)(ws + off); off += (size_t)HC * IN_F * 2;
  unsigned short* w2h = (unsigned short*)(ws + off); off += (size_t)HC * HC * 2;
  unsigned short* w2l = (unsigned short*)(ws + off); off += (size_t)HC * HC * 2;
  unsigned short* w3h = (unsigned short*)(ws + off); off += (size_t)HC * HC * 2;
  unsigned short* w3l = (unsigned short*)(ws + off); off += (size_t)HC * HC * 2;
  float* als    = (float*)(ws + off); off += (size_t)N_NODES * HEADS * 4;
  float* ald    = (float*)(ws + off); off += (size_t)N_NODES * HEADS * 4;
  float* pooled = (float*)(ws + off); off += (size_t)G_GRAPHS * HC * 4;
  int*   cnt    = (int*)(ws + off);   off += (size_t)N_NODES * 4;
  int*   cursor = (int*)(ws + off);   off += (size_t)N_NODES * 4;
  int*   csrsrc = (int*)(ws + off);   off += (size_t)ET * 4;
  int*   rowptr = (int*)(ws + off);   off += (size_t)(N_NODES + 1) * 4;

  // --- splits (independent of CSR) ---
  int nx = N_NODES * IN_F;
  split_kernel<<<(nx / 4 + 255) / 256, 256, 0, stream>>>(x, xhi, xlo, nx);
  split_kernel<<<(HC * IN_F / 4 + 255) / 256, 256, 0, stream>>>(W1, w1h, w1l, HC * IN_F);
  split_kernel<<<(HC * HC / 4 + 255) / 256, 256, 0, stream>>>(W2, w2h, w2l, HC * HC);
  split_kernel<<<(HC * HC / 4 + 255) / 256, 256, 0, stream>>>(W3, w3h, w3l, HC * HC);

  // --- CSR build ---
  hipMemsetAsync(cnt, 0, (size_t)N_NODES * 4, stream);
  hipMemsetAsync(pooled, 0, (size_t)G_GRAPHS * HC * 4, stream);
  count_kernel<<<(ET + 255) / 256, 256, 0, stream>>>(ei, cnt);
  scan_kernel<<<1, 1024, 0, stream>>>(cnt, rowptr, cursor);
  scatter_kernel<<<(ET + 255) / 256, 256, 0, stream>>>(ei, cursor, csrsrc);

  dim3 gemm_grid((N_NODES + 127) / 128);
  int agg_grid = N_NODES / 4;  // exact: 50000 % 4 == 0

  // --- layer 1 ---
  mfma_gemm_kernel<IN_F><<<gemm_grid, 256, 0, stream>>>(xhi, xlo, w1h, w1l, as1, ad1, hbuf16, als, ald);
  agg_kernel<0><<<agg_grid, 256, 0, stream>>>(hbuf16, als, ald, rowptr, csrsrc, b1, ahi, alo, nullptr, nullptr);
  // --- layer 2 ---
  mfma_gemm_kernel<HC><<<gemm_grid, 256, 0, stream>>>(ahi, alo, w2h, w2l, as2, ad2, hbuf16, als, ald);
  agg_kernel<0><<<agg_grid, 256, 0, stream>>>(hbuf16, als, ald, rowptr, csrsrc, b2, ahi, alo, nullptr, nullptr);
  // --- layer 3 (fused mean-pool accumulate) ---
  mfma_gemm_kernel<HC><<<gemm_grid, 256, 0, stream>>>(ahi, alo, w3h, w3l, as3, ad3, hbuf16, als, ald);
  agg_kernel<1><<<agg_grid, 256, 0, stream>>>(hbuf16, als, ald, rowptr, csrsrc, b3, nullptr, nullptr, pooled, batch);

  // --- pool divide + MLP ---
  pool_div_kernel<<<G_GRAPHS, 256, 0, stream>>>(pooled, batch);
  mlp_kernel<<<G_GRAPHS, 64, 0, stream>>>(pooled, fc1w, fc1b, fc2w, fc2b, out);
}

// Round 6
// 460.467 us; speedup vs baseline: 2.6657x; 1.1574x over previous
//
#include <hip/hip_runtime.h>
#include <hip/hip_bf16.h>

#define N_NODES 50000
#define E_EDGES 800000
#define ET (E_EDGES + N_NODES)
#define G_GRAPHS 64
#define IN_F 128
#define HID 64
#define HEADS 4
#define HC (HID * HEADS)
#define NC 2
#define SLOPE 0.2f
#define L2E 1.4426950408889634f

typedef float f32x4 __attribute__((ext_vector_type(4)));
typedef __bf16 bf16x8 __attribute__((ext_vector_type(8)));
typedef unsigned short us8 __attribute__((ext_vector_type(8)));
typedef unsigned short us4 __attribute__((ext_vector_type(4)));
typedef _Float16 h16x4 __attribute__((ext_vector_type(4)));

#define MFMA16(a, b, c) \
  __builtin_amdgcn_mfma_f32_16x16x32_bf16(__builtin_bit_cast(bf16x8, (a)), \
                                          __builtin_bit_cast(bf16x8, (b)), (c), 0, 0, 0)

__device__ inline unsigned short f2bf_rne(float f) {
  unsigned u = __builtin_bit_cast(unsigned, f);
  u += 0x7fffu + ((u >> 16) & 1u);
  return (unsigned short)(u >> 16);
}
__device__ inline float bf2f(unsigned short h) {
  unsigned u = ((unsigned)h) << 16;
  return __builtin_bit_cast(float, u);
}

// ---------------- fused split/cast kernel ----------------
// x -> bf16 (hi only; A-side of GEMM is single bf16 now)
// W1,W2,W3 -> bf16 hi/lo pairs (weight error must stay ~2^-16: systematic across nodes)

__device__ inline void split4(const float* __restrict__ in, unsigned short* __restrict__ hi,
                              unsigned short* __restrict__ lo, int i) {
  float4 v = *(const float4*)&in[i];
  float f[4] = {v.x, v.y, v.z, v.w};
  us4 h, l;
#pragma unroll
  for (int j = 0; j < 4; j++) {
    unsigned short hb = f2bf_rne(f[j]);
    h[j] = hb;
    l[j] = f2bf_rne(f[j] - bf2f(hb));
  }
  *(us4*)&hi[i] = h;
  *(us4*)&lo[i] = l;
}

#define QX (N_NODES * IN_F / 4)
#define QW1 (HC * IN_F / 4)
#define QW2 (HC * HC / 4)
#define QTOT (QX + QW1 + 2 * QW2)

__global__ __launch_bounds__(256) void split_all_kernel(
    const float* __restrict__ x, const float* __restrict__ W1,
    const float* __restrict__ W2, const float* __restrict__ W3,
    unsigned short* __restrict__ xhi,
    unsigned short* __restrict__ w1h, unsigned short* __restrict__ w1l,
    unsigned short* __restrict__ w2h, unsigned short* __restrict__ w2l,
    unsigned short* __restrict__ w3h, unsigned short* __restrict__ w3l) {
  int q = blockIdx.x * 256 + threadIdx.x;
  if (q < QX) {
    int i = q * 4;
    float4 v = *(const float4*)&x[i];
    float f[4] = {v.x, v.y, v.z, v.w};
    us4 h;
#pragma unroll
    for (int j = 0; j < 4; j++) h[j] = f2bf_rne(f[j]);
    *(us4*)&xhi[i] = h;
  } else if (q < QX + QW1) {
    split4(W1, w1h, w1l, (q - QX) * 4);
  } else if (q < QX + QW1 + QW2) {
    split4(W2, w2h, w2l, (q - QX - QW1) * 4);
  } else {
    split4(W3, w3h, w3l, (q - QX - QW1 - QW2) * 4);
  }
}

// ---------------- CSR build ----------------

__global__ void count_kernel(const int* __restrict__ ei, int* __restrict__ cnt) {
  int e = blockIdx.x * blockDim.x + threadIdx.x;
  if (e >= ET) return;
  int dst = (e < E_EDGES) ? ei[E_EDGES + e] : (e - E_EDGES);
  atomicAdd(&cnt[dst], 1);
}

// 3-dispatch scan: per-block scan -> scan of partials -> add offsets
#define SCAN_BLOCKS ((N_NODES + 255) / 256)

__global__ __launch_bounds__(256) void scan1_kernel(const int* __restrict__ cnt,
                                                    int* __restrict__ incl_buf,
                                                    int* __restrict__ partial) {
  __shared__ int ws[4];
  int tid = threadIdx.x, b = blockIdx.x;
  int wave = tid >> 6, lane = tid & 63;
  int i = b * 256 + tid;
  int v = (i < N_NODES) ? cnt[i] : 0;
  int x = v;
#pragma unroll
  for (int off = 1; off < 64; off <<= 1) {
    int t = __shfl_up(x, off, 64);
    if (lane >= off) x += t;
  }
  if (lane == 63) ws[wave] = x;
  __syncthreads();
  if (tid == 0) {
    int s = 0;
#pragma unroll
    for (int w = 0; w < 4; w++) { int t = ws[w]; ws[w] = s; s += t; }
    partial[b] = s;
  }
  __syncthreads();
  if (i < N_NODES) incl_buf[i] = x + ws[wave];
}

__global__ __launch_bounds__(256) void scan2_kernel(int* __restrict__ partial) {
  __shared__ int ws[4];
  int tid = threadIdx.x;
  int wave = tid >> 6, lane = tid & 63;
  int v = (tid < SCAN_BLOCKS) ? partial[tid] : 0;
  int x = v;
#pragma unroll
  for (int off = 1; off < 64; off <<= 1) {
    int t = __shfl_up(x, off, 64);
    if (lane >= off) x += t;
  }
  if (lane == 63) ws[wave] = x;
  __syncthreads();
  if (tid == 0) {
    int s = 0;
#pragma unroll
    for (int w = 0; w < 4; w++) { int t = ws[w]; ws[w] = s; s += t; }
  }
  __syncthreads();
  partial[tid] = x + ws[wave] - v;  // exclusive prefix
}

__global__ __launch_bounds__(256) void scan3_kernel(const int* __restrict__ cnt,
                                                    int* __restrict__ incl_buf,
                                                    const int* __restrict__ partial,
                                                    int* __restrict__ rowptr,
                                                    int* __restrict__ cursor) {
  int tid = threadIdx.x, b = blockIdx.x;
  int i = b * 256 + tid;
  if (i >= N_NODES) return;
  int incl = incl_buf[i] + partial[b];
  rowptr[i + 1] = incl;
  cursor[i] = incl - cnt[i];
  if (i == 0) rowptr[0] = 0;
}

__global__ void scatter_kernel(const int* __restrict__ ei, int* __restrict__ cursor,
                               int* __restrict__ csr_src) {
  int e = blockIdx.x * blockDim.x + threadIdx.x;
  if (e >= ET) return;
  int src, dst;
  if (e < E_EDGES) { src = ei[e]; dst = ei[E_EDGES + e]; }
  else { src = e - E_EDGES; dst = src; }
  int pos = atomicAdd(&cursor[dst], 1);
  csr_src[pos] = src;
}

// ---------------- 2-term split-bf16 MFMA GEMM: h = A @ (Whi+Wlo)^T ----------------
// A single bf16 (per-node rounding washes out in mean-pool); W bf16 hi/lo (systematic).
// BM=128, BN=256 (all 4 heads), BK=32. 4 waves; wave w = head w, 128x64 sub-tile.

template <int K>
__global__ __launch_bounds__(256) void mfma_gemm_kernel(
    const unsigned short* __restrict__ A,
    const unsigned short* __restrict__ Whi, const unsigned short* __restrict__ Wlo,
    const float* __restrict__ a_s, const float* __restrict__ a_d,
    _Float16* __restrict__ hbuf16, float* __restrict__ als, float* __restrict__ ald) {
  __shared__ unsigned short As[4 * 128 * 8];      // 8 KB
  __shared__ unsigned short Bs[2][4 * 256 * 8];   // 32 KB

  int t = threadIdx.x;
  int mt = blockIdx.x;
  int w = t >> 6, lane = t & 63, lr = lane & 15, kg = lane >> 4;
  int srow = t >> 2, skg = t & 3;   // staging coords

  f32x4 acc[8][4];
#pragma unroll
  for (int m = 0; m < 8; m++)
#pragma unroll
    for (int nf = 0; nf < 4; nf++) {
      f32x4 z = {0.f, 0.f, 0.f, 0.f};
      acc[m][nf] = z;
    }

  for (int k0 = 0; k0 < K; k0 += 32) {
    us8 va[2];
#pragma unroll
    for (int i = 0; i < 2; i++) {
      int agrow = mt * 128 + srow + 64 * i;
      if (agrow < N_NODES) {
        va[i] = *(const us8*)&A[(size_t)agrow * K + k0 + skg * 8];
      } else {
        us8 z = {0, 0, 0, 0, 0, 0, 0, 0};
        va[i] = z;
      }
    }
    us8 vb0[4], vb1[4];
#pragma unroll
    for (int c = 0; c < 4; c++) {
      int n = srow + 64 * c;
      vb0[c] = *(const us8*)&Whi[(size_t)n * K + k0 + skg * 8];
      vb1[c] = *(const us8*)&Wlo[(size_t)n * K + k0 + skg * 8];
    }
    __syncthreads();
#pragma unroll
    for (int i = 0; i < 2; i++) {
      int row = srow + 64 * i;
      *(us8*)&As[(skg * 128 + row) * 8] = va[i];
    }
#pragma unroll
    for (int c = 0; c < 4; c++) {
      int n = srow + 64 * c;
      *(us8*)&Bs[0][(skg * 256 + n) * 8] = vb0[c];
      *(us8*)&Bs[1][(skg * 256 + n) * 8] = vb1[c];
    }
    __syncthreads();

    us8 bh[4], bl[4];
#pragma unroll
    for (int nf = 0; nf < 4; nf++) {
      int n = w * 64 + nf * 16 + lr;
      bh[nf] = *(us8*)&Bs[0][(kg * 256 + n) * 8];
      bl[nf] = *(us8*)&Bs[1][(kg * 256 + n) * 8];
    }
#pragma unroll
    for (int m = 0; m < 8; m++) {
      int row = m * 16 + lr;
      us8 ah = *(us8*)&As[(kg * 128 + row) * 8];
#pragma unroll
      for (int nf = 0; nf < 4; nf++) {
        acc[m][nf] = MFMA16(ah, bh[nf], acc[m][nf]);
        acc[m][nf] = MFMA16(ah, bl[nf], acc[m][nf]);
      }
    }
  }

  // epilogue: store h (fp16) + reduce als/ald (scaled by log2e) for head w.
  // C layout: col = nf*16 + lr, row = m*16 + kg*4 + r
  int head = w;
  float asv[4], adv[4];
#pragma unroll
  for (int nf = 0; nf < 4; nf++) {
    asv[nf] = a_s[head * HID + nf * 16 + lr];
    adv[nf] = a_d[head * HID + nf * 16 + lr];
  }
#pragma unroll
  for (int m = 0; m < 8; m++) {
#pragma unroll
    for (int r = 0; r < 4; r++) {
      int grow = mt * 128 + m * 16 + kg * 4 + r;
      float ps = 0.f, pd = 0.f;
#pragma unroll
      for (int nf = 0; nf < 4; nf++) {
        float v = acc[m][nf][r];
        ps += v * asv[nf];
        pd += v * adv[nf];
        if (grow < N_NODES)
          hbuf16[(size_t)grow * HC + head * 64 + nf * 16 + lr] = (_Float16)v;
      }
#pragma unroll
      for (int msk = 1; msk < 16; msk <<= 1) {
        ps += __shfl_xor(ps, msk, 64);
        pd += __shfl_xor(pd, msk, 64);
      }
      if (lr == 0 && grow < N_NODES) {
        als[grow * HEADS + head] = ps * L2E;
        ald[grow * HEADS + head] = pd * L2E;
      }
    }
  }
}

// ---------------- per-destination softmax + aggregate (one wave per node) ----------------
// MODE 0: relu + single-bf16 output (layers 1,2)
// MODE 1: + bias, no relu, fused mean-pool atomic accumulation (layer 3)

template <int MODE>
__global__ __launch_bounds__(256) void agg_kernel(
    const _Float16* __restrict__ hbuf16, const float* __restrict__ alsE,
    const float* __restrict__ aldE, const int* __restrict__ rowptr,
    const int* __restrict__ csr_src, const float* __restrict__ bias,
    unsigned short* __restrict__ ohi, float* __restrict__ pooled,
    const int* __restrict__ batch) {
  int wave = threadIdx.x >> 6;
  int lane = threadIdx.x & 63;
  int v = blockIdx.x * 4 + wave;
  int head = lane >> 4;
  float myald = aldE[(unsigned)v * HEADS + head];
  int beg = rowptr[v], end = rowptr[v + 1];

  float den = 0.f;
  f32x4 acc = {0.f, 0.f, 0.f, 0.f};
  const _Float16* hp = hbuf16 + (lane << 2);
#pragma unroll 4
  for (int i = beg; i < end; i++) {
    int s = csr_src[i];
    float a = alsE[(unsigned)s * HEADS + head] + myald;
    a = fmaxf(a, SLOPE * a);                    // leaky (log2e-scaled domain)
    float ex = __builtin_amdgcn_exp2f(a);
    den += ex;
    h16x4 hv = *(const h16x4*)(hp + ((unsigned)s << 8));
    acc[0] += (float)hv[0] * ex;
    acc[1] += (float)hv[1] * ex;
    acc[2] += (float)hv[2] * ex;
    acc[3] += (float)hv[3] * ex;
  }
  float inv = 1.0f / (den + 1e-16f);
  float4 bv = *(const float4*)&bias[lane * 4];
  float o[4];
  o[0] = acc[0] * inv + bv.x;
  o[1] = acc[1] * inv + bv.y;
  o[2] = acc[2] * inv + bv.z;
  o[3] = acc[3] * inv + bv.w;

  if (MODE == 0) {
    us4 h;
#pragma unroll
    for (int j = 0; j < 4; j++) {
      o[j] = fmaxf(o[j], 0.f);
      h[j] = f2bf_rne(o[j]);
    }
    *(us4*)&ohi[(size_t)v * HC + lane * 4] = h;
  } else {
    __shared__ float pacc[4][HC];
    __shared__ int pg[4];
    f32x4 ov = {o[0], o[1], o[2], o[3]};
    *(f32x4*)&pacc[wave][lane * 4] = ov;
    if (lane == 0) pg[wave] = batch[v];
    __syncthreads();
    int c = threadIdx.x;
    int g0 = pg[0], g1 = pg[1], g2 = pg[2], g3 = pg[3];
    if (g0 == g1 && g1 == g2 && g2 == g3) {
      atomicAdd(&pooled[g0 * HC + c], pacc[0][c] + pacc[1][c] + pacc[2][c] + pacc[3][c]);
    } else {
      atomicAdd(&pooled[g0 * HC + c], pacc[0][c]);
      atomicAdd(&pooled[g1 * HC + c], pacc[1][c]);
      atomicAdd(&pooled[g2 * HC + c], pacc[2][c]);
      atomicAdd(&pooled[g3 * HC + c], pacc[3][c]);
    }
  }
}

// ---------------- MLP head (fused mean-divide) ----------------

__global__ __launch_bounds__(64) void mlp_kernel(const float* __restrict__ pooled_sum,
                                                 const int* __restrict__ batch,
                                                 const float* __restrict__ w1,
                                                 const float* __restrict__ b1,
                                                 const float* __restrict__ w2,
                                                 const float* __restrict__ b2,
                                                 float* __restrict__ out) {
  int g = blockIdx.x;
  int j = threadIdx.x;
  int lo = 0, hi = N_NODES;
  while (lo < hi) { int mid = (lo + hi) >> 1; if (batch[mid] < g) lo = mid + 1; else hi = mid; }
  int start = lo;
  hi = N_NODES;
  while (lo < hi) { int mid = (lo + hi) >> 1; if (batch[mid] < g + 1) lo = mid + 1; else hi = mid; }
  float invc = 1.0f / fmaxf((float)(lo - start), 1.0f);
  __shared__ float z[HID];
  float acc = 0.f;
  for (int k = 0; k < HC; k++) acc += pooled_sum[g * HC + k] * w1[j * HC + k];
  z[j] = fmaxf(acc * invc + b1[j], 0.f);
  __syncthreads();
  if (j < NC) {
    float o = b2[j];
    for (int k = 0; k < HID; k++) o += z[k] * w2[j * HID + k];
    out[g * NC + j] = o;
  }
}

// ---------------- launch ----------------

extern "C" void kernel_launch(void* const* d_in, const int* in_sizes, int n_in,
                              void* d_out, int out_size, void* d_ws, size_t ws_size,
                              hipStream_t stream) {
  const float* x    = (const float*)d_in[0];
  const int*   ei   = (const int*)d_in[1];
  const int*   batch= (const int*)d_in[2];
  const float* W1   = (const float*)d_in[3];
  const float* as1  = (const float*)d_in[4];
  const float* ad1  = (const float*)d_in[5];
  const float* b1   = (const float*)d_in[6];
  const float* W2   = (const float*)d_in[7];
  const float* as2  = (const float*)d_in[8];
  const float* ad2  = (const float*)d_in[9];
  const float* b2   = (const float*)d_in[10];
  const float* W3   = (const float*)d_in[11];
  const float* as3  = (const float*)d_in[12];
  const float* ad3  = (const float*)d_in[13];
  const float* b3   = (const float*)d_in[14];
  const float* fc1w = (const float*)d_in[15];
  const float* fc1b = (const float*)d_in[16];
  const float* fc2w = (const float*)d_in[17];
  const float* fc2b = (const float*)d_in[18];
  float* out = (float*)d_out;

  char* ws = (char*)d_ws;
  size_t off = 0;
  _Float16* hbuf16 = (_Float16*)(ws + off); off += (size_t)N_NODES * HC * 2;  // 25.6 MB
  unsigned short* ahi = (unsigned short*)(ws + off); off += (size_t)N_NODES * HC * 2;
  unsigned short* xhi = (unsigned short*)(ws + off); off += (size_t)N_NODES * IN_F * 2;
  unsigned short* w1h = (unsigned short*)(ws + off); off += (size_t)HC * IN_F * 2;
  unsigned short* w1l = (unsigned short*)(ws + off); off += (size_t)HC * IN_F * 2;
  unsigned short* w2h = (unsigned short*)(ws + off); off += (size_t)HC * HC * 2;
  unsigned short* w2l = (unsigned short*)(ws + off); off += (size_t)HC * HC * 2;
  unsigned short* w3h = (unsigned short*)(ws + off); off += (size_t)HC * HC * 2;
  unsigned short* w3l = (unsigned short*)(ws + off); off += (size_t)HC * HC * 2;
  float* als    = (float*)(ws + off); off += (size_t)N_NODES * HEADS * 4;
  float* ald    = (float*)(ws + off); off += (size_t)N_NODES * HEADS * 4;
  float* pooled = (float*)(ws + off); off += (size_t)G_GRAPHS * HC * 4;
  int*   cnt    = (int*)(ws + off);   off += (size_t)N_NODES * 4;
  int*   cursor = (int*)(ws + off);   off += (size_t)N_NODES * 4;
  int*   csrsrc = (int*)(ws + off);   off += (size_t)ET * 4;
  int*   rowptr = (int*)(ws + off);   off += (size_t)(N_NODES + 1) * 4;
  int*   partial= (int*)(ws + off);   off += 256 * 4;

  // --- fused splits (independent of CSR) ---
  split_all_kernel<<<(QTOT + 255) / 256, 256, 0, stream>>>(
      x, W1, W2, W3, xhi, w1h, w1l, w2h, w2l, w3h, w3l);

  // --- CSR build ---
  hipMemsetAsync(cnt, 0, (size_t)N_NODES * 4, stream);
  hipMemsetAsync(pooled, 0, (size_t)G_GRAPHS * HC * 4, stream);
  count_kernel<<<(ET + 255) / 256, 256, 0, stream>>>(ei, cnt);
  scan1_kernel<<<SCAN_BLOCKS, 256, 0, stream>>>(cnt, cursor, partial);
  scan2_kernel<<<1, 256, 0, stream>>>(partial);
  scan3_kernel<<<SCAN_BLOCKS, 256, 0, stream>>>(cnt, cursor, partial, rowptr, cursor);
  scatter_kernel<<<(ET + 255) / 256, 256, 0, stream>>>(ei, cursor, csrsrc);

  dim3 gemm_grid((N_NODES + 127) / 128);
  int agg_grid = N_NODES / 4;

  // --- layer 1 ---
  mfma_gemm_kernel<IN_F><<<gemm_grid, 256, 0, stream>>>(xhi, w1h, w1l, as1, ad1, hbuf16, als, ald);
  agg_kernel<0><<<agg_grid, 256, 0, stream>>>(hbuf16, als, ald, rowptr, csrsrc, b1, ahi, nullptr, nullptr);
  // --- layer 2 ---
  mfma_gemm_kernel<HC><<<gemm_grid, 256, 0, stream>>>(ahi, w2h, w2l, as2, ad2, hbuf16, als, ald);
  agg_kernel<0><<<agg_grid, 256, 0, stream>>>(hbuf16, als, ald, rowptr, csrsrc, b2, ahi, nullptr, nullptr);
  // --- layer 3 (fused mean-pool accumulate) ---
  mfma_gemm_kernel<HC><<<gemm_grid, 256, 0, stream>>>(ahi, w3h, w3l, as3, ad3, hbuf16, als, ald);
  agg_kernel<1><<<agg_grid, 256, 0, stream>>>(hbuf16, als, ald, rowptr, csrsrc, b3, nullptr, pooled, batch);

  // --- MLP (with fused mean divide) ---
  mlp_kernel<<<G_GRAPHS, 64, 0, stream>>>(pooled, batch, fc1w, fc1b, fc2w, fc2b, out);
}

// Round 7
// 428.347 us; speedup vs baseline: 2.8655x; 1.0750x over previous
//
#include <hip/hip_runtime.h>
#include <hip/hip_bf16.h>

#define N_NODES 50000
#define E_EDGES 800000
#define ET (E_EDGES + N_NODES)
#define G_GRAPHS 64
#define IN_F 128
#define HID 64
#define HEADS 4
#define HC (HID * HEADS)
#define NC 2
#define SLOPE 0.2f
#define L2E 1.4426950408889634f

typedef float f32x4 __attribute__((ext_vector_type(4)));
typedef __bf16 bf16x8 __attribute__((ext_vector_type(8)));
typedef unsigned short us8 __attribute__((ext_vector_type(8)));
typedef unsigned short us4 __attribute__((ext_vector_type(4)));
typedef _Float16 h16x4 __attribute__((ext_vector_type(4)));

#define MFMA16(a, b, c) \
  __builtin_amdgcn_mfma_f32_16x16x32_bf16(__builtin_bit_cast(bf16x8, (a)), \
                                          __builtin_bit_cast(bf16x8, (b)), (c), 0, 0, 0)

__device__ inline unsigned short f2bf_rne(float f) {
  unsigned u = __builtin_bit_cast(unsigned, f);
  u += 0x7fffu + ((u >> 16) & 1u);
  return (unsigned short)(u >> 16);
}
__device__ inline float bf2f(unsigned short h) {
  unsigned u = ((unsigned)h) << 16;
  return __builtin_bit_cast(float, u);
}

// ---------------- fused split/cast kernel ----------------

__device__ inline void split4(const float* __restrict__ in, unsigned short* __restrict__ hi,
                              unsigned short* __restrict__ lo, int i) {
  float4 v = *(const float4*)&in[i];
  float f[4] = {v.x, v.y, v.z, v.w};
  us4 h, l;
#pragma unroll
  for (int j = 0; j < 4; j++) {
    unsigned short hb = f2bf_rne(f[j]);
    h[j] = hb;
    l[j] = f2bf_rne(f[j] - bf2f(hb));
  }
  *(us4*)&hi[i] = h;
  *(us4*)&lo[i] = l;
}

#define QX (N_NODES * IN_F / 4)
#define QW1 (HC * IN_F / 4)
#define QW2 (HC * HC / 4)
#define QTOT (QX + QW1 + 2 * QW2)

__global__ __launch_bounds__(256) void split_all_kernel(
    const float* __restrict__ x, const float* __restrict__ W1,
    const float* __restrict__ W2, const float* __restrict__ W3,
    unsigned short* __restrict__ xhi,
    unsigned short* __restrict__ w1h, unsigned short* __restrict__ w1l,
    unsigned short* __restrict__ w2h, unsigned short* __restrict__ w2l,
    unsigned short* __restrict__ w3h, unsigned short* __restrict__ w3l) {
  int q = blockIdx.x * 256 + threadIdx.x;
  if (q < QX) {
    int i = q * 4;
    float4 v = *(const float4*)&x[i];
    float f[4] = {v.x, v.y, v.z, v.w};
    us4 h;
#pragma unroll
    for (int j = 0; j < 4; j++) h[j] = f2bf_rne(f[j]);
    *(us4*)&xhi[i] = h;
  } else if (q < QX + QW1) {
    split4(W1, w1h, w1l, (q - QX) * 4);
  } else if (q < QX + QW1 + QW2) {
    split4(W2, w2h, w2l, (q - QX - QW1) * 4);
  } else {
    split4(W3, w3h, w3l, (q - QX - QW1 - QW2) * 4);
  }
}

// ---------------- CSR build ----------------

__global__ void count_kernel(const int* __restrict__ ei, int* __restrict__ cnt) {
  int e = blockIdx.x * blockDim.x + threadIdx.x;
  if (e >= ET) return;
  int dst = (e < E_EDGES) ? ei[E_EDGES + e] : (e - E_EDGES);
  atomicAdd(&cnt[dst], 1);
}

#define SCAN_BLOCKS ((N_NODES + 255) / 256)

__global__ __launch_bounds__(256) void scan1_kernel(const int* __restrict__ cnt,
                                                    int* __restrict__ incl_buf,
                                                    int* __restrict__ partial) {
  __shared__ int ws[4];
  int tid = threadIdx.x, b = blockIdx.x;
  int wave = tid >> 6, lane = tid & 63;
  int i = b * 256 + tid;
  int v = (i < N_NODES) ? cnt[i] : 0;
  int x = v;
#pragma unroll
  for (int off = 1; off < 64; off <<= 1) {
    int t = __shfl_up(x, off, 64);
    if (lane >= off) x += t;
  }
  if (lane == 63) ws[wave] = x;
  __syncthreads();
  if (tid == 0) {
    int s = 0;
#pragma unroll
    for (int w = 0; w < 4; w++) { int t = ws[w]; ws[w] = s; s += t; }
    partial[b] = s;
  }
  __syncthreads();
  if (i < N_NODES) incl_buf[i] = x + ws[wave];
}

__global__ __launch_bounds__(256) void scan2_kernel(int* __restrict__ partial) {
  __shared__ int ws[4];
  int tid = threadIdx.x;
  int wave = tid >> 6, lane = tid & 63;
  int v = (tid < SCAN_BLOCKS) ? partial[tid] : 0;
  int x = v;
#pragma unroll
  for (int off = 1; off < 64; off <<= 1) {
    int t = __shfl_up(x, off, 64);
    if (lane >= off) x += t;
  }
  if (lane == 63) ws[wave] = x;
  __syncthreads();
  if (tid == 0) {
    int s = 0;
#pragma unroll
    for (int w = 0; w < 4; w++) { int t = ws[w]; ws[w] = s; s += t; }
  }
  __syncthreads();
  partial[tid] = x + ws[wave] - v;
}

__global__ __launch_bounds__(256) void scan3_kernel(const int* __restrict__ cnt,
                                                    int* __restrict__ incl_buf,
                                                    const int* __restrict__ partial,
                                                    int* __restrict__ rowptr,
                                                    int* __restrict__ cursor) {
  int tid = threadIdx.x, b = blockIdx.x;
  int i = b * 256 + tid;
  if (i >= N_NODES) return;
  int incl = incl_buf[i] + partial[b];
  rowptr[i + 1] = incl;
  cursor[i] = incl - cnt[i];
  if (i == 0) rowptr[0] = 0;
}

__global__ void scatter_kernel(const int* __restrict__ ei, int* __restrict__ cursor,
                               int* __restrict__ csr_src) {
  int e = blockIdx.x * blockDim.x + threadIdx.x;
  if (e >= ET) return;
  int src, dst;
  if (e < E_EDGES) { src = ei[e]; dst = ei[E_EDGES + e]; }
  else { src = e - E_EDGES; dst = src; }
  int pos = atomicAdd(&cursor[dst], 1);
  csr_src[pos] = src;
}

// ---------------- 2-term split-bf16 MFMA GEMM: h = A @ (Whi+Wlo)^T ----------------
// BM=64 (782 blocks: fills 256 CUs 3.05x -> small tail), BN=256, BK=32.
// 4 waves; wave w = head w, 64x64 sub-tile.

template <int K>
__global__ __launch_bounds__(256) void mfma_gemm_kernel(
    const unsigned short* __restrict__ A,
    const unsigned short* __restrict__ Whi, const unsigned short* __restrict__ Wlo,
    const float* __restrict__ a_s, const float* __restrict__ a_d,
    _Float16* __restrict__ hbuf16, float* __restrict__ als, float* __restrict__ ald) {
  __shared__ unsigned short As[4 * 64 * 8];       // 4 KB
  __shared__ unsigned short Bs[2][4 * 256 * 8];   // 32 KB

  int t = threadIdx.x;
  int mt = blockIdx.x;
  int w = t >> 6, lane = t & 63, lr = lane & 15, kg = lane >> 4;
  int srow = t >> 2, skg = t & 3;

  f32x4 acc[4][4];
#pragma unroll
  for (int m = 0; m < 4; m++)
#pragma unroll
    for (int nf = 0; nf < 4; nf++) {
      f32x4 z = {0.f, 0.f, 0.f, 0.f};
      acc[m][nf] = z;
    }

  int agrow = mt * 64 + srow;
  bool avalid = agrow < N_NODES;

  for (int k0 = 0; k0 < K; k0 += 32) {
    us8 va;
    if (avalid) {
      va = *(const us8*)&A[(size_t)agrow * K + k0 + skg * 8];
    } else {
      us8 z = {0, 0, 0, 0, 0, 0, 0, 0};
      va = z;
    }
    us8 vb0[4], vb1[4];
#pragma unroll
    for (int c = 0; c < 4; c++) {
      int n = srow + 64 * c;
      vb0[c] = *(const us8*)&Whi[(size_t)n * K + k0 + skg * 8];
      vb1[c] = *(const us8*)&Wlo[(size_t)n * K + k0 + skg * 8];
    }
    __syncthreads();
    *(us8*)&As[(skg * 64 + srow) * 8] = va;
#pragma unroll
    for (int c = 0; c < 4; c++) {
      int n = srow + 64 * c;
      *(us8*)&Bs[0][(skg * 256 + n) * 8] = vb0[c];
      *(us8*)&Bs[1][(skg * 256 + n) * 8] = vb1[c];
    }
    __syncthreads();

    us8 bh[4], bl[4];
#pragma unroll
    for (int nf = 0; nf < 4; nf++) {
      int n = w * 64 + nf * 16 + lr;
      bh[nf] = *(us8*)&Bs[0][(kg * 256 + n) * 8];
      bl[nf] = *(us8*)&Bs[1][(kg * 256 + n) * 8];
    }
#pragma unroll
    for (int m = 0; m < 4; m++) {
      int row = m * 16 + lr;
      us8 ah = *(us8*)&As[(kg * 64 + row) * 8];
#pragma unroll
      for (int nf = 0; nf < 4; nf++) {
        acc[m][nf] = MFMA16(ah, bh[nf], acc[m][nf]);
        acc[m][nf] = MFMA16(ah, bl[nf], acc[m][nf]);
      }
    }
  }

  // epilogue: store h (fp16) + reduce als/ald (scaled by log2e) for head w.
  // C layout: col = nf*16 + lr, row = m*16 + kg*4 + r
  int head = w;
  float asv[4], adv[4];
#pragma unroll
  for (int nf = 0; nf < 4; nf++) {
    asv[nf] = a_s[head * HID + nf * 16 + lr];
    adv[nf] = a_d[head * HID + nf * 16 + lr];
  }
#pragma unroll
  for (int m = 0; m < 4; m++) {
#pragma unroll
    for (int r = 0; r < 4; r++) {
      int grow = mt * 64 + m * 16 + kg * 4 + r;
      float ps = 0.f, pd = 0.f;
#pragma unroll
      for (int nf = 0; nf < 4; nf++) {
        float v = acc[m][nf][r];
        ps += v * asv[nf];
        pd += v * adv[nf];
        if (grow < N_NODES)
          hbuf16[(size_t)grow * HC + head * 64 + nf * 16 + lr] = (_Float16)v;
      }
#pragma unroll
      for (int msk = 1; msk < 16; msk <<= 1) {
        ps += __shfl_xor(ps, msk, 64);
        pd += __shfl_xor(pd, msk, 64);
      }
      if (lr == 0 && grow < N_NODES) {
        als[grow * HEADS + head] = ps * L2E;
        ald[grow * HEADS + head] = pd * L2E;
      }
    }
  }
}

// ---------------- dual-stream per-destination softmax + aggregate ----------------
// One wave handles TWO dst nodes with interleaved edge streams: doubles in-flight
// gathers (latency-bound kernel) and cuts wave-iterations from n0+n1 to max(n0,n1).
// Clamped index + predicated-zero weight keeps math exact (self-loops => n >= 1).
// MODE 0: relu + bf16 output (layers 1,2). MODE 1: bias + fused mean-pool (layer 3).
// Grid: N_NODES/8 = 6250 blocks exactly.

template <int MODE>
__global__ __launch_bounds__(256) void agg_kernel(
    const _Float16* __restrict__ hbuf16, const float* __restrict__ alsE,
    const float* __restrict__ aldE, const int* __restrict__ rowptr,
    const int* __restrict__ csr_src, const float* __restrict__ bias,
    unsigned short* __restrict__ ohi, float* __restrict__ pooled,
    const int* __restrict__ batch) {
  int wave = threadIdx.x >> 6;
  int lane = threadIdx.x & 63;
  int v0 = blockIdx.x * 8 + wave * 2;
  int v1 = v0 + 1;
  int head = lane >> 4;
  float ald0 = aldE[(unsigned)v0 * HEADS + head];
  float ald1 = aldE[(unsigned)v1 * HEADS + head];
  int beg0 = rowptr[v0], n0 = rowptr[v0 + 1] - beg0;
  int beg1 = rowptr[v1], n1 = rowptr[v1 + 1] - beg1;
  int n = max(n0, n1);

  float den0 = 0.f, den1 = 0.f;
  f32x4 acc0 = {0.f, 0.f, 0.f, 0.f};
  f32x4 acc1 = {0.f, 0.f, 0.f, 0.f};
  const _Float16* hp = hbuf16 + (lane << 2);
#pragma unroll 2
  for (int i = 0; i < n; i++) {
    int s0 = csr_src[beg0 + min(i, n0 - 1)];
    int s1 = csr_src[beg1 + min(i, n1 - 1)];
    float a0 = alsE[(unsigned)s0 * HEADS + head] + ald0;
    float a1 = alsE[(unsigned)s1 * HEADS + head] + ald1;
    a0 = fmaxf(a0, SLOPE * a0);
    a1 = fmaxf(a1, SLOPE * a1);
    float ex0 = (i < n0) ? __builtin_amdgcn_exp2f(a0) : 0.f;
    float ex1 = (i < n1) ? __builtin_amdgcn_exp2f(a1) : 0.f;
    h16x4 h0 = *(const h16x4*)(hp + ((unsigned)s0 << 8));
    h16x4 h1 = *(const h16x4*)(hp + ((unsigned)s1 << 8));
    den0 += ex0; den1 += ex1;
    acc0[0] += (float)h0[0] * ex0; acc0[1] += (float)h0[1] * ex0;
    acc0[2] += (float)h0[2] * ex0; acc0[3] += (float)h0[3] * ex0;
    acc1[0] += (float)h1[0] * ex1; acc1[1] += (float)h1[1] * ex1;
    acc1[2] += (float)h1[2] * ex1; acc1[3] += (float)h1[3] * ex1;
  }
  float inv0 = 1.0f / (den0 + 1e-16f);
  float inv1 = 1.0f / (den1 + 1e-16f);
  float4 bv = *(const float4*)&bias[lane * 4];
  float o0[4], o1[4];
  o0[0] = acc0[0] * inv0 + bv.x; o0[1] = acc0[1] * inv0 + bv.y;
  o0[2] = acc0[2] * inv0 + bv.z; o0[3] = acc0[3] * inv0 + bv.w;
  o1[0] = acc1[0] * inv1 + bv.x; o1[1] = acc1[1] * inv1 + bv.y;
  o1[2] = acc1[2] * inv1 + bv.z; o1[3] = acc1[3] * inv1 + bv.w;

  if (MODE == 0) {
    us4 h0, h1;
#pragma unroll
    for (int j = 0; j < 4; j++) {
      h0[j] = f2bf_rne(fmaxf(o0[j], 0.f));
      h1[j] = f2bf_rne(fmaxf(o1[j], 0.f));
    }
    *(us4*)&ohi[(size_t)v0 * HC + lane * 4] = h0;
    *(us4*)&ohi[(size_t)v1 * HC + lane * 4] = h1;
  } else {
    __shared__ float pacc[8][HC];
    __shared__ int pg[8];
    f32x4 ov0 = {o0[0], o0[1], o0[2], o0[3]};
    f32x4 ov1 = {o1[0], o1[1], o1[2], o1[3]};
    *(f32x4*)&pacc[wave * 2][lane * 4] = ov0;
    *(f32x4*)&pacc[wave * 2 + 1][lane * 4] = ov1;
    if (lane == 0) {
      pg[wave * 2] = batch[v0];
      pg[wave * 2 + 1] = batch[v1];
    }
    __syncthreads();
    int c = threadIdx.x;
    float s = pacc[0][c];
    int gcur = pg[0];
#pragma unroll
    for (int wv = 1; wv < 8; wv++) {
      if (pg[wv] != gcur) {
        atomicAdd(&pooled[gcur * HC + c], s);
        s = 0.f;
        gcur = pg[wv];
      }
      s += pacc[wv][c];
    }
    atomicAdd(&pooled[gcur * HC + c], s);
  }
}

// ---------------- MLP head (fused mean-divide) ----------------

__global__ __launch_bounds__(64) void mlp_kernel(const float* __restrict__ pooled_sum,
                                                 const int* __restrict__ batch,
                                                 const float* __restrict__ w1,
                                                 const float* __restrict__ b1,
                                                 const float* __restrict__ w2,
                                                 const float* __restrict__ b2,
                                                 float* __restrict__ out) {
  int g = blockIdx.x;
  int j = threadIdx.x;
  int lo = 0, hi = N_NODES;
  while (lo < hi) { int mid = (lo + hi) >> 1; if (batch[mid] < g) lo = mid + 1; else hi = mid; }
  int start = lo;
  hi = N_NODES;
  while (lo < hi) { int mid = (lo + hi) >> 1; if (batch[mid] < g + 1) lo = mid + 1; else hi = mid; }
  float invc = 1.0f / fmaxf((float)(lo - start), 1.0f);
  __shared__ float z[HID];
  float acc = 0.f;
  for (int k = 0; k < HC; k++) acc += pooled_sum[g * HC + k] * w1[j * HC + k];
  z[j] = fmaxf(acc * invc + b1[j], 0.f);
  __syncthreads();
  if (j < NC) {
    float o = b2[j];
    for (int k = 0; k < HID; k++) o += z[k] * w2[j * HID + k];
    out[g * NC + j] = o;
  }
}

// ---------------- launch ----------------

extern "C" void kernel_launch(void* const* d_in, const int* in_sizes, int n_in,
                              void* d_out, int out_size, void* d_ws, size_t ws_size,
                              hipStream_t stream) {
  const float* x    = (const float*)d_in[0];
  const int*   ei   = (const int*)d_in[1];
  const int*   batch= (const int*)d_in[2];
  const float* W1   = (const float*)d_in[3];
  const float* as1  = (const float*)d_in[4];
  const float* ad1  = (const float*)d_in[5];
  const float* b1   = (const float*)d_in[6];
  const float* W2   = (const float*)d_in[7];
  const float* as2  = (const float*)d_in[8];
  const float* ad2  = (const float*)d_in[9];
  const float* b2   = (const float*)d_in[10];
  const float* W3   = (const float*)d_in[11];
  const float* as3  = (const float*)d_in[12];
  const float* ad3  = (const float*)d_in[13];
  const float* b3   = (const float*)d_in[14];
  const float* fc1w = (const float*)d_in[15];
  const float* fc1b = (const float*)d_in[16];
  const float* fc2w = (const float*)d_in[17];
  const float* fc2b = (const float*)d_in[18];
  float* out = (float*)d_out;

  char* ws = (char*)d_ws;
  size_t off = 0;
  _Float16* hbuf16 = (_Float16*)(ws + off); off += (size_t)N_NODES * HC * 2;
  unsigned short* ahi = (unsigned short*)(ws + off); off += (size_t)N_NODES * HC * 2;
  unsigned short* xhi = (unsigned short*)(ws + off); off += (size_t)N_NODES * IN_F * 2;
  unsigned short* w1h = (unsigned short*)(ws + off); off += (size_t)HC * IN_F * 2;
  unsigned short* w1l = (unsigned short*)(ws + off); off += (size_t)HC * IN_F * 2;
  unsigned short* w2h = (unsigned short*)(ws + off); off += (size_t)HC * HC * 2;
  unsigned short* w2l = (unsigned short*)(ws + off); off += (size_t)HC * HC * 2;
  unsigned short* w3h = (unsigned short*)(ws + off); off += (size_t)HC * HC * 2;
  unsigned short* w3l = (unsigned short*)(ws + off); off += (size_t)HC * HC * 2;
  float* als    = (float*)(ws + off); off += (size_t)N_NODES * HEADS * 4;
  float* ald    = (float*)(ws + off); off += (size_t)N_NODES * HEADS * 4;
  float* pooled = (float*)(ws + off); off += (size_t)G_GRAPHS * HC * 4;
  int*   cnt    = (int*)(ws + off);   off += (size_t)N_NODES * 4;
  int*   cursor = (int*)(ws + off);   off += (size_t)N_NODES * 4;
  int*   csrsrc = (int*)(ws + off);   off += (size_t)ET * 4;
  int*   rowptr = (int*)(ws + off);   off += (size_t)(N_NODES + 1) * 4;
  int*   partial= (int*)(ws + off);   off += 256 * 4;

  // --- fused splits (independent of CSR) ---
  split_all_kernel<<<(QTOT + 255) / 256, 256, 0, stream>>>(
      x, W1, W2, W3, xhi, w1h, w1l, w2h, w2l, w3h, w3l);

  // --- CSR build ---
  hipMemsetAsync(cnt, 0, (size_t)N_NODES * 4, stream);
  hipMemsetAsync(pooled, 0, (size_t)G_GRAPHS * HC * 4, stream);
  count_kernel<<<(ET + 255) / 256, 256, 0, stream>>>(ei, cnt);
  scan1_kernel<<<SCAN_BLOCKS, 256, 0, stream>>>(cnt, cursor, partial);
  scan2_kernel<<<1, 256, 0, stream>>>(partial);
  scan3_kernel<<<SCAN_BLOCKS, 256, 0, stream>>>(cnt, cursor, partial, rowptr, cursor);
  scatter_kernel<<<(ET + 255) / 256, 256, 0, stream>>>(ei, cursor, csrsrc);

  dim3 gemm_grid((N_NODES + 63) / 64);
  int agg_grid = N_NODES / 8;  // exact: 50000 % 8 == 0

  // --- layer 1 ---
  mfma_gemm_kernel<IN_F><<<gemm_grid, 256, 0, stream>>>(xhi, w1h, w1l, as1, ad1, hbuf16, als, ald);
  agg_kernel<0><<<agg_grid, 256, 0, stream>>>(hbuf16, als, ald, rowptr, csrsrc, b1, ahi, nullptr, nullptr);
  // --- layer 2 ---
  mfma_gemm_kernel<HC><<<gemm_grid, 256, 0, stream>>>(ahi, w2h, w2l, as2, ad2, hbuf16, als, ald);
  agg_kernel<0><<<agg_grid, 256, 0, stream>>>(hbuf16, als, ald, rowptr, csrsrc, b2, ahi, nullptr, nullptr);
  // --- layer 3 (fused mean-pool accumulate) ---
  mfma_gemm_kernel<HC><<<gemm_grid, 256, 0, stream>>>(ahi, w3h, w3l, as3, ad3, hbuf16, als, ald);
  agg_kernel<1><<<agg_grid, 256, 0, stream>>>(hbuf16, als, ald, rowptr, csrsrc, b3, nullptr, pooled, batch);

  // --- MLP (with fused mean divide) ---
  mlp_kernel<<<G_GRAPHS, 64, 0, stream>>>(pooled, batch, fc1w, fc1b, fc2w, fc2b, out);
}